// Round 13
// baseline (151.121 us; speedup 1.0000x reference)
//
#include <hip/hip_runtime.h>
#include <hip/hip_bf16.h>
#include <cmath>

typedef __bf16 bf16;
typedef __attribute__((ext_vector_type(4))) __bf16 bf16x4;
typedef __attribute__((ext_vector_type(8))) __bf16 bf16x8;
typedef __attribute__((ext_vector_type(4))) float f32x4;

#define B_ 2
#define S_ 2048
#define D_ 1024
#define N_ 16
#define H_ 64
// 0.125 * log2(e): folded into Q at projection so QK^T emits exp2-domain scores
#define QSCALE 0.18033688011112042f

__device__ __forceinline__ void gload16(const bf16* g, bf16* l) {
  __builtin_amdgcn_global_load_lds(
      (const __attribute__((address_space(1))) void*)(g),
      (__attribute__((address_space(3))) void*)(l), 16, 0, 0);
}

__device__ __forceinline__ f32x4 mfma16(bf16x8 a, bf16x8 b, f32x4 c) {
  return __builtin_amdgcn_mfma_f32_16x16x32_bf16(a, b, c, 0, 0, 0);
}

__device__ __forceinline__ f32x4 zero4() {
  f32x4 v = {0.0f, 0.0f, 0.0f, 0.0f};
  return v;
}

// ---------------------------------------------------------------------------
// Prep (merged, 3072 blocks x 256):
//   bi <  2048: residual fp32 -> bf16 (8 elems/thread)
//   2048..2815: QKV weight transpose, head z: [1024][64] fp32 -> [64][1024] bf16
//   2816..3071: Wo transpose: [1024][1024] fp32 -> bf16 transposed
// ---------------------------------------------------------------------------
__global__ __launch_bounds__(256) void prep_kernel(
    const float* __restrict__ residual, bf16* __restrict__ Abf,
    const float* __restrict__ Wk, const float* __restrict__ Wq,
    const float* __restrict__ Wv, bf16* __restrict__ Wkt,
    const float* __restrict__ Wo, bf16* __restrict__ Wot) {
  __shared__ bf16 t[64][72];
  const int bi = blockIdx.x;
  if (bi < 2048) {
    const int id = bi * 256 + threadIdx.x;
    const float4* p = (const float4*)(residual + (size_t)id * 8);
    float4 v0 = p[0], v1 = p[1];
    bf16x8 o;
    o[0] = (bf16)v0.x; o[1] = (bf16)v0.y; o[2] = (bf16)v0.z; o[3] = (bf16)v0.w;
    o[4] = (bf16)v1.x; o[5] = (bf16)v1.y; o[6] = (bf16)v1.z; o[7] = (bf16)v1.w;
    *(bf16x8*)(Abf + (size_t)id * 8) = o;
    return;
  }
  const float* ing; bf16* outg; int C, r0, c0;
  if (bi < 2816) {
    const int idx = bi - 2048, z = idx >> 4, xr = idx & 15;
    const float* W = (z < 16) ? Wk : (z < 32) ? Wq : Wv;
    ing = W + (size_t)(z & 15) * (1024 * 64);
    outg = Wkt + (size_t)z * (64 * 1024);
    C = 64; r0 = xr * 64; c0 = 0;
  } else {
    const int idx = bi - 2816, xr = idx & 15, yc = idx >> 4;
    ing = Wo; outg = Wot; C = 1024; r0 = xr * 64; c0 = yc * 64;
  }
  const int t8 = threadIdx.x & 7, trow = threadIdx.x >> 3;
#pragma unroll
  for (int p = 0; p < 2; ++p) {
    int r = trow + p * 32;
    const float4* src = (const float4*)(ing + (size_t)(r0 + r) * C + c0 + t8 * 8);
    float4 v0 = src[0], v1 = src[1];
    bf16x8 o;
    o[0] = (bf16)v0.x; o[1] = (bf16)v0.y; o[2] = (bf16)v0.z; o[3] = (bf16)v0.w;
    o[4] = (bf16)v1.x; o[5] = (bf16)v1.y; o[6] = (bf16)v1.z; o[7] = (bf16)v1.w;
    *(bf16x8*)(&t[r][t8 * 8]) = o;
  }
  __syncthreads();
#pragma unroll
  for (int p = 0; p < 2; ++p) {
    int c = trow + p * 32;
    bf16x8 v;
#pragma unroll
    for (int j = 0; j < 8; ++j) v[j] = t[t8 * 8 + j][c];
    *(bf16x8*)(outg + (size_t)(c0 + c) * 1024 + r0 + t8 * 8) = v;
  }
}

// ---------------------------------------------------------------------------
// V-work (merged, 3072 blocks x 256):
//   bi < 2048: sufv_tot — per-(hd, 32-row seg) column totals of Vp
//   else     : bf16 transpose Vp [S][H] -> Vtp [H][S] per head
// ---------------------------------------------------------------------------
__global__ __launch_bounds__(256) void vwork_kernel(
    const bf16* __restrict__ Vp, float* __restrict__ tot,
    bf16* __restrict__ Vtp) {
  __shared__ bf16 t[64][72];
  __shared__ float red[4][64];
  const int bi = blockIdx.x;
  if (bi < 2048) {
    const int hd = bi >> 6, seg = bi & 63;
    const int h = threadIdx.x & 63, sub = threadIdx.x >> 6;
    const bf16* Vh = Vp + (size_t)hd * S_ * H_;
    float a = 0.0f;
    const int k0 = seg * 32 + sub * 8;
#pragma unroll
    for (int k = 0; k < 8; ++k) a += (float)Vh[(size_t)(k0 + k) * H_ + h];
    red[sub][h] = a;
    __syncthreads();
    if (sub == 0)
      tot[(hd * 64 + seg) * 64 + h] = red[0][h] + red[1][h] + red[2][h] + red[3][h];
    return;
  }
  const int idx = bi - 2048, z = idx >> 5, xr = idx & 31;
  const bf16* ing = Vp + (size_t)z * (S_ * H_);
  bf16* outg = Vtp + (size_t)z * (S_ * H_);
  const int r0 = xr * 64;
  const int t8 = threadIdx.x & 7, trow = threadIdx.x >> 3;
#pragma unroll
  for (int p = 0; p < 2; ++p) {
    int r = trow + p * 32;
    bf16x8 v = *(const bf16x8*)(ing + (size_t)(r0 + r) * 64 + t8 * 8);
    *(bf16x8*)(&t[r][t8 * 8]) = v;
  }
  __syncthreads();
#pragma unroll
  for (int p = 0; p < 2; ++p) {
    int c = trow + p * 32;
    bf16x8 v;
#pragma unroll
    for (int j = 0; j < 8; ++j) v[j] = t[t8 * 8 + j][c];
    *(bf16x8*)(outg + (size_t)c * 2048 + r0 + t8 * 8) = v;
  }
}

// ---------------------------------------------------------------------------
// Suffix-V scan: Suf[hd][q][h] = sum_{k>q} V[hd][k][h], bf16 IN-PLACE over Vp.
// ---------------------------------------------------------------------------
__global__ __launch_bounds__(64) void sufv_scan_kernel(
    bf16* __restrict__ VS, const float* __restrict__ tot) {
  const int hd = blockIdx.x, seg = blockIdx.y, h = threadIdx.x;
  bf16* Vh = VS + (size_t)hd * S_ * H_;  // in: V, out: Suf (in-place)
  float a = 0.0f;
  for (int s2 = seg + 1; s2 < 64; ++s2) a += tot[(hd * 64 + s2) * 64 + h];
  for (int k = seg * 32 + 31; k >= seg * 32; --k) {
    const float v = (float)Vh[(size_t)k * H_ + h];  // read BEFORE overwrite
    Vh[(size_t)k * H_ + h] = (bf16)a;
    a += v;
  }
}

// ---------------------------------------------------------------------------
// QKV projection GEMM v3: 256x192 tile -> grid 16x16 = 256 blocks = 1/CU on
// ALL CUs (v2's 192-block grid left 25% of the machine idle). Same 4-phase
// counted-vmcnt skeleton as R11 (verified); B-slot padded to 256 rows so every
// wave issues exactly 2 loads per STG -> vmcnt ledger identical to R11.
// z==1 (queries) epilogue pre-scales by QSCALE. 512 threads, LDS 128KB.
// ---------------------------------------------------------------------------
__global__ __launch_bounds__(512) void gemm_proj_kernel(
    const bf16* __restrict__ A, const bf16* __restrict__ Bt,
    const float* __restrict__ bk, const float* __restrict__ bq,
    const float* __restrict__ bv, bf16* __restrict__ proj_base) {
  __shared__ bf16 As[2][2][256 * 32];
  __shared__ bf16 Bs[2][2][256 * 32];  // rows 192..255 staged, never read
  const int tid = threadIdx.x;
  const int w = tid >> 6, l = tid & 63, lan = l & 15, grp = l >> 4;
  const int wm128 = (w >> 2) * 128, wn48 = (w & 3) * 48;
  const int bid = blockIdx.x;
  const int bid2 = (bid & 7) * 32 + (bid >> 3);  // XCD-contiguous remap
  const int m0 = (bid2 >> 4) * 256, n0 = (bid2 & 15) * 192;
  const int posx = (grp ^ ((lan >> 1) & 3)) << 3;  // swizzled read chunk

#define STG(LDS_, GP_, rb_, buf_, kh_, kb_)                                    \
  do {                                                                         \
    _Pragma("unroll") for (int jj = 0; jj < 2; ++jj) {                         \
      const int ci = jj * 512 + tid;                                           \
      const int rw = ci >> 2, cp = ci & 3;                                     \
      const int gg = cp ^ ((rw >> 1) & 3);                                     \
      gload16(GP_ + (size_t)((rb_) + rw) * 1024 + (kb_) + (kh_) * 32 + gg * 8, \
              &LDS_[buf_][kh_][(jj * 512 + w * 64) * 8]);                      \
    }                                                                          \
  } while (0)

  f32x4 acc[8][3];
#pragma unroll
  for (int i = 0; i < 8; ++i)
#pragma unroll
    for (int jv = 0; jv < 3; ++jv) acc[i][jv] = zero4();

  bf16x8 b[3];

#define DO_PHASE(buf_, mq_, kk_, READB_)                                       \
  do {                                                                         \
    if (READB_) {                                                              \
      _Pragma("unroll") for (int nf = 0; nf < 3; ++nf)                         \
        b[nf] = *(const bf16x8*)(&Bs[buf_][kk_][(wn48 + nf * 16 + lan) * 32 + posx]); \
    }                                                                          \
    bf16x8 a[4];                                                               \
    _Pragma("unroll") for (int mf = 0; mf < 4; ++mf)                           \
      a[mf] = *(const bf16x8*)(&As[buf_][kk_][(wm128 + (mq_) * 64 + mf * 16 + lan) * 32 + posx]); \
    __builtin_amdgcn_s_setprio(1);                                             \
    _Pragma("unroll") for (int mf = 0; mf < 4; ++mf)                           \
      _Pragma("unroll") for (int nf = 0; nf < 3; ++nf)                         \
        acc[(mq_) * 4 + mf][nf] = mfma16(a[mf], b[nf], acc[(mq_) * 4 + mf][nf]); \
    __builtin_amdgcn_s_setprio(0);                                             \
  } while (0)

  // prologue: all 4 slots of K-step 0 into buf 0
  STG(As, A, m0, 0, 0, 0);
  STG(Bs, Bt, n0, 0, 0, 0);
  STG(As, A, m0, 0, 1, 0);
  STG(Bs, Bt, n0, 0, 1, 0);

  for (int t = 0; t < 15; ++t) {
    const int buf = t & 1;
    const int nkb = (t + 1) * 64;
    STG(As, A, m0, buf ^ 1, 0, nkb);
    asm volatile("s_waitcnt vmcnt(6)" ::: "memory");
    __builtin_amdgcn_s_barrier();
    asm volatile("" ::: "memory");
    DO_PHASE(buf, 0, 0, true);
    STG(Bs, Bt, n0, buf ^ 1, 0, nkb);
    asm volatile("" ::: "memory");
    __builtin_amdgcn_s_barrier();
    asm volatile("" ::: "memory");
    DO_PHASE(buf, 1, 0, false);
    STG(As, A, m0, buf ^ 1, 1, nkb);
    asm volatile("s_waitcnt vmcnt(6)" ::: "memory");
    __builtin_amdgcn_s_barrier();
    asm volatile("" ::: "memory");
    DO_PHASE(buf, 0, 1, true);
    STG(Bs, Bt, n0, buf ^ 1, 1, nkb);
    asm volatile("" ::: "memory");
    __builtin_amdgcn_s_barrier();
    asm volatile("" ::: "memory");
    DO_PHASE(buf, 1, 1, false);
  }
  {
    asm volatile("s_waitcnt vmcnt(4)" ::: "memory");
    __builtin_amdgcn_s_barrier();
    asm volatile("" ::: "memory");
    DO_PHASE(1, 0, 0, true);
    DO_PHASE(1, 1, 0, false);
    asm volatile("s_waitcnt vmcnt(0)" ::: "memory");
    __builtin_amdgcn_s_barrier();
    asm volatile("" ::: "memory");
    DO_PHASE(1, 0, 1, true);
    DO_PHASE(1, 1, 1, false);
  }
#undef STG
#undef DO_PHASE

  // epilogue: scatter to [z][b][n][s][h] + bias (+QSCALE for queries).
  // col base n0+wn48+nf*16 is 16-aligned -> z uniform across the 16 lanes.
#pragma unroll
  for (int nf = 0; nf < 3; ++nf) {
    const int c = n0 + wn48 + nf * 16 + lan;  // 0..3071
    const int zc = c >> 10, c10 = c & 1023;
    const float* bp = (zc == 0) ? bk : (zc == 1 ? bq : bv);
    const float bs = bp[c10];
    const float osc = (zc == 1) ? QSCALE : 1.0f;
    bf16* Out = proj_base + (size_t)zc * ((size_t)B_ * N_ * S_ * H_);
    const int n = c10 >> 6, h = c10 & 63;
#pragma unroll
    for (int am = 0; am < 8; ++am) {
#pragma unroll
      for (int r = 0; r < 4; ++r) {
        const int m = m0 + wm128 + am * 16 + grp * 4 + r;
        const int bb = m >> 11, s = m & 2047;
        Out[((size_t)((bb * N_ + n) * S_ + s)) * H_ + h] = (bf16)((acc[am][nf][r] + bs) * osc);
      }
    }
  }
}

// ---------------------------------------------------------------------------
// Output projection GEMM (swizzled LDS, XCD-remapped): grid 256 (1D), 256 thr.
// ---------------------------------------------------------------------------
__global__ __launch_bounds__(256) void gemm_out_kernel(
    const bf16* __restrict__ A, const bf16* __restrict__ Bt,
    const float* __restrict__ bias, float* __restrict__ Out) {
  __shared__ bf16 As[128 * 64];
  __shared__ bf16 Bs[128 * 64];
  const int tid = threadIdx.x;
  const int w = tid >> 6, l = tid & 63, lan = l & 15, grp = l >> 4;
  const int mb = (w >> 1) * 64, nb = (w & 1) * 64;
  const int bid = blockIdx.x;
  const int bid2 = (bid & 7) * 32 + (bid >> 3);  // XCD-contiguous remap
  const int m0 = (bid2 >> 3) * 128, n0 = (bid2 & 7) * 128;
  const int lrow8 = l >> 3;
  const int swl = ((l & 7) ^ lrow8) * 8;
  const int l7 = lan & 7;

  f32x4 acc[4][4];
#pragma unroll
  for (int i = 0; i < 4; ++i)
#pragma unroll
    for (int j = 0; j < 4; ++j) acc[i][j] = zero4();

  for (int kb = 0; kb < 1024; kb += 64) {
    __syncthreads();
#pragma unroll
    for (int i = 0; i < 4; ++i) {
      int ch = w * 4 + i;
      gload16(A + (size_t)(m0 + ch * 8 + lrow8) * 1024 + kb + swl, As + ch * 512);
      gload16(Bt + (size_t)(n0 + ch * 8 + lrow8) * 1024 + kb + swl, Bs + ch * 512);
    }
    __syncthreads();
#pragma unroll
    for (int kk = 0; kk < 2; ++kk) {
      bf16x8 a[4], b[4];
#pragma unroll
      for (int mf = 0; mf < 4; ++mf)
        a[mf] = *(const bf16x8*)(As + (mb + mf * 16 + lan) * 64 + (((grp + kk * 4) ^ l7) << 3));
#pragma unroll
      for (int nf = 0; nf < 4; ++nf)
        b[nf] = *(const bf16x8*)(Bs + (nb + nf * 16 + lan) * 64 + (((grp + kk * 4) ^ l7) << 3));
#pragma unroll
      for (int mf = 0; mf < 4; ++mf)
#pragma unroll
        for (int nf = 0; nf < 4; ++nf)
          acc[mf][nf] = mfma16(a[mf], b[nf], acc[mf][nf]);
    }
  }
#pragma unroll
  for (int nf = 0; nf < 4; ++nf) {
    int c = n0 + nb + nf * 16 + lan;
    float bs = bias[c];
#pragma unroll
    for (int mf = 0; mf < 4; ++mf) {
#pragma unroll
      for (int r = 0; r < 4; ++r) {
        int m = m0 + mb + mf * 16 + grp * 4 + r;
        Out[(size_t)m * 1024 + c] = acc[mf][nf][r] + bs;
      }
    }
  }
}

// ---------------------------------------------------------------------------
// Attention — R7 structure + exp2-domain Q (prescale isolated from R8's pair;
// the psf ones-MFMA is NOT reintroduced). Split-k, balanced:
//   quarter 0 (bi<256):  x=15-wv, k-tiles [0, x+1)     -> fp32 partial A
//   quarter 1 (bi<512):  x=15-wv, k-tiles [x+1, 2x+2)  -> fp32 partial B
//   quarter 2 (bi<768):  x=wv,    k-tiles [0, 2x+2)    -> final Wtd rows
// grid 768, block 256 (4 waves x 32 q-rows). Suf is bf16.
// ---------------------------------------------------------------------------
__global__ __launch_bounds__(256) void attn_kernel(
    const bf16* __restrict__ Qp, const bf16* __restrict__ Kp,
    const bf16* __restrict__ Vt, const bf16* __restrict__ Suf,
    bf16* __restrict__ Wtd, float* __restrict__ PoA, float* __restrict__ PoB,
    float* __restrict__ PpA, float* __restrict__ PpB) {
  __shared__ bf16 Ks[2][64 * 64];
  __shared__ bf16 Vs[2][64 * 64];
  __shared__ bf16 Ps[4][32 * 72];
  const int tid = threadIdx.x;
  const int w = tid >> 6, l = tid & 63, lan = l & 15, grp = l >> 4;
  const int bi = blockIdx.x;
  const int qq = bi >> 8;
  const int j = bi & 255;
  const int hd = j & 31, wv = j >> 5;
  int x, t0, t1;
  if (qq == 0)      { x = 15 - wv; t0 = 0;     t1 = x + 1; }
  else if (qq == 1) { x = 15 - wv; t0 = x + 1; t1 = 2 * x + 2; }
  else              { x = wv;      t0 = 0;     t1 = 2 * x + 2; }
  const int qw = x * 128 + w * 32;
  const bf16* Qh = Qp + (size_t)hd * S_ * H_;
  const bf16* Kh = Kp + (size_t)hd * S_ * H_;
  const bf16* Vh = Vt + (size_t)hd * H_ * S_;
  const bf16* Sufh = Suf + (size_t)hd * S_ * H_;
  const int lrow8 = l >> 3;
  const int swl = ((l & 7) ^ lrow8) * 8;
  const int l7 = lan & 7;

#define STAGE(buf, kb_)                                                        \
  do {                                                                         \
    _Pragma("unroll") for (int i2 = 0; i2 < 2; ++i2) {                         \
      int ch = w * 2 + i2;                                                     \
      gload16(Kh + (size_t)((kb_) + ch * 8 + lrow8) * H_ + swl,                \
              &Ks[buf][ch * 512]);                                             \
      gload16(Vh + (size_t)(ch * 8 + lrow8) * S_ + (kb_) + swl,                \
              &Vs[buf][ch * 512]);                                             \
    }                                                                          \
  } while (0)

  // Q fragments (B-operand for swapped QK^T: n=lan=q, k=grp*8+j (+32*kf))
  bf16x8 qa[2][2];
#pragma unroll
  for (int qt = 0; qt < 2; ++qt)
#pragma unroll
    for (int kf = 0; kf < 2; ++kf)
      qa[qt][kf] = *(const bf16x8*)(Qh + (size_t)(qw + qt * 16 + lan) * H_ + grp * 8 + kf * 32);

  f32x4 o[2][4];
  float psum[2] = {0.0f, 0.0f};
#pragma unroll
  for (int qt = 0; qt < 2; ++qt)
#pragma unroll
    for (int hf = 0; hf < 4; ++hf) o[qt][hf] = zero4();

  bf16* Pw = &Ps[w][0];

  STAGE(0, t0 * 64);
  for (int tt = t0; tt < t1; ++tt) {
    const int kb = tt * 64;
    const int cur = (tt - t0) & 1;
    if (tt + 1 < t1) {
      STAGE(cur ^ 1, kb + 64);
      asm volatile("s_waitcnt vmcnt(4)" ::: "memory");
    } else {
      asm volatile("s_waitcnt vmcnt(0)" ::: "memory");
    }
    __builtin_amdgcn_s_barrier();

    if (kb <= qw + 31) {
      const bf16* Kc = &Ks[cur][0];
      const bf16* Vc = &Vs[cur][0];

      // --- swapped QK^T: s2[k2][qt], col=lan=q, row=grp*4+r=k ---
      f32x4 s2[4][2];
#pragma unroll
      for (int k2 = 0; k2 < 4; ++k2)
#pragma unroll
        for (int qt = 0; qt < 2; ++qt) s2[k2][qt] = zero4();
      __builtin_amdgcn_s_setprio(1);
#pragma unroll
      for (int kf = 0; kf < 2; ++kf) {
        bf16x8 kfr[4];
#pragma unroll
        for (int k2 = 0; k2 < 4; ++k2)
          kfr[k2] = *(const bf16x8*)(Kc + (k2 * 16 + lan) * 64 + (((grp + kf * 4) ^ l7) << 3));
#pragma unroll
        for (int k2 = 0; k2 < 4; ++k2)
#pragma unroll
          for (int qt = 0; qt < 2; ++qt)
            s2[k2][qt] = mfma16(kfr[k2], qa[qt][kf], s2[k2][qt]);
      }
      __builtin_amdgcn_s_setprio(0);

      // --- p = exp2(s) (Q pre-scaled), diag-mask, psum, pack -> b64 write ---
      const bool maskt = (kb + 63 > qw);
#pragma unroll
      for (int qt = 0; qt < 2; ++qt) {
        const int q_g = qw + qt * 16 + lan;
#pragma unroll
        for (int k2 = 0; k2 < 4; ++k2) {
          f32x4 p;
#pragma unroll
          for (int r = 0; r < 4; ++r) p[r] = exp2f(s2[k2][qt][r]);
          if (maskt) {
            const int kg0 = kb + k2 * 16 + grp * 4;
#pragma unroll
            for (int r = 0; r < 4; ++r)
              if (kg0 + r > q_g) p[r] = 0.0f;
          }
          psum[qt] += (p[0] + p[1]) + (p[2] + p[3]);
          unsigned plo, phi;
          asm("v_cvt_pk_bf16_f32 %0, %1, %2" : "=v"(plo) : "v"(p[0]), "v"(p[1]));
          asm("v_cvt_pk_bf16_f32 %0, %1, %2" : "=v"(phi) : "v"(p[2]), "v"(p[3]));
          uint2 u; u.x = plo; u.y = phi;
          *(uint2*)(Pw + (qt * 16 + lan) * 72 + k2 * 16 + grp * 4) = u;
        }
      }

      // --- PV ---
      __builtin_amdgcn_s_setprio(1);
#pragma unroll
      for (int ks = 0; ks < 2; ++ks) {
        bf16x8 pa[2], vb[4];
#pragma unroll
        for (int qt = 0; qt < 2; ++qt)
          pa[qt] = *(const bf16x8*)(Pw + (qt * 16 + lan) * 72 + grp * 8 + ks * 32);
#pragma unroll
        for (int hf = 0; hf < 4; ++hf)
          vb[hf] = *(const bf16x8*)(Vc + (hf * 16 + lan) * 64 + (((grp + ks * 4) ^ l7) << 3));
#pragma unroll
        for (int qt = 0; qt < 2; ++qt)
#pragma unroll
          for (int hf = 0; hf < 4; ++hf)
            o[qt][hf] = mfma16(pa[qt], vb[hf], o[qt][hf]);
      }
      __builtin_amdgcn_s_setprio(0);
    }
    __builtin_amdgcn_s_barrier();
  }
#undef STAGE

  // psum: reduce over grp (lanes sharing lan); q = qt*16+lan
#pragma unroll
  for (int qt = 0; qt < 2; ++qt) {
    psum[qt] += __shfl_xor(psum[qt], 16);
    psum[qt] += __shfl_xor(psum[qt], 32);
  }

  if (qq == 2) {
    // final: o = (o_causal + SufV) / (psum + (2047-q))
    const size_t outbase = (size_t)(hd >> 4) * S_ * (N_ * H_) + (size_t)(hd & 15) * H_;
#pragma unroll
    for (int qt = 0; qt < 2; ++qt) {
#pragma unroll
      for (int r = 0; r < 4; ++r) {
        const int q_g = qw + qt * 16 + grp * 4 + r;
        const float ps = __shfl(psum[qt], grp * 4 + r);
        const float inv = 1.0f / (ps + (float)(2047 - q_g));
#pragma unroll
        for (int hf = 0; hf < 4; ++hf) {
          const int h = hf * 16 + lan;
          const float suf = (float)Sufh[(size_t)q_g * H_ + h];
          Wtd[outbase + (size_t)q_g * (N_ * H_) + h] = (bf16)((o[qt][hf][r] + suf) * inv);
        }
      }
    }
  } else {
    // partial: raw fp32 o + row psums
    float* Po = (qq == 0) ? PoA : PoB;
    float* Pp = (qq == 0) ? PpA : PpB;
    const int pb = (hd * 8 + (x - 8)) * 128 + w * 32;
#pragma unroll
    for (int qt = 0; qt < 2; ++qt) {
#pragma unroll
      for (int r = 0; r < 4; ++r) {
        const int rl = qt * 16 + grp * 4 + r;
        const float ps = __shfl(psum[qt], grp * 4 + r);
        if (lan == 0) Pp[pb + rl] = ps;
#pragma unroll
        for (int hf = 0; hf < 4; ++hf)
          Po[(size_t)(pb + rl) * 64 + hf * 16 + lan] = o[qt][hf][r];
      }
    }
  }
}

// ---------------------------------------------------------------------------
// Combine: for x in 8..15, Wtd = (PoA + PoB + Suf) / (PpA + PpB + 2047-q).
// ---------------------------------------------------------------------------
__global__ __launch_bounds__(256) void combine_kernel(
    const float* __restrict__ PoA, const float* __restrict__ PoB,
    const float* __restrict__ PpA, const float* __restrict__ PpB,
    const bf16* __restrict__ Suf, bf16* __restrict__ Wtd) {
  const int hd = blockIdx.x >> 3, xi = blockIdx.x & 7;
  const int x = xi + 8;
  const int pb = (hd * 8 + xi) * 128;
  const size_t outbase = (size_t)(hd >> 4) * S_ * (N_ * H_) + (size_t)(hd & 15) * H_;
#pragma unroll
  for (int it = 0; it < 8; ++it) {
    const int e = it * 256 + threadIdx.x;  // 0..2047 float4 units
    const int rl = e >> 4, h4 = (e & 15) * 4;
    const int q_g = x * 128 + rl;
    const float Z = PpA[pb + rl] + PpB[pb + rl] + (float)(2047 - q_g);
    const float inv = 1.0f / Z;
    const float4 a = *(const float4*)(PoA + (size_t)(pb + rl) * 64 + h4);
    const float4 b = *(const float4*)(PoB + (size_t)(pb + rl) * 64 + h4);
    const bf16x4 s4 = *(const bf16x4*)(Suf + ((size_t)hd * S_ + q_g) * 64 + h4);
    bf16x4 ov;
    ov[0] = (bf16)((a.x + b.x + (float)s4[0]) * inv);
    ov[1] = (bf16)((a.y + b.y + (float)s4[1]) * inv);
    ov[2] = (bf16)((a.z + b.z + (float)s4[2]) * inv);
    ov[3] = (bf16)((a.w + b.w + (float)s4[3]) * inv);
    *(bf16x4*)(Wtd + outbase + (size_t)q_g * (N_ * H_) + h4) = ov;
  }
}

// ---------------------------------------------------------------------------
extern "C" void kernel_launch(void* const* d_in, const int* in_sizes, int n_in,
                              void* d_out, int out_size, void* d_ws, size_t ws_size,
                              hipStream_t stream) {
  const float* residual = (const float*)d_in[0];
  const float* Wk = (const float*)d_in[1];
  const float* Wq = (const float*)d_in[2];
  const float* Wv = (const float*)d_in[3];
  const float* Wo = (const float*)d_in[4];
  const float* Bk = (const float*)d_in[5];
  const float* Bq = (const float*)d_in[6];
  const float* Bv = (const float*)d_in[7];
  const float* Bo = (const float*)d_in[8];
  float* outp = (float*)d_out;

  // ws layout (peak 48MB — proven safe; do NOT exceed):
  //   [ 0.. 8) Abf (prep out, gemm_proj A)       -> Wtd (attn/combine out)
  //   [ 8..10) Wot (live to end)
  //   [10..16) Wkt (gemm_proj B, [3072][1024])   -> PpA, PpB, tot
  //   [16..24) Kp   [24..32) Qp
  //   [32..40) Vp (proj V) -> in-place Suf (bf16) via sufv_scan
  //   [40..48) Vtp
  // d_out (16MB fp32): PoA [0..8MB) + PoB [8..16MB) until gemm_out overwrites.
  char* ws = (char*)d_ws;
  const size_t MB = 1024 * 1024;
  bf16* Abf = (bf16*)(ws + 0 * MB);
  bf16* Wot = (bf16*)(ws + 8 * MB);
  bf16* Wkt = (bf16*)(ws + 10 * MB);
  bf16* Kp  = (bf16*)(ws + 16 * MB);
  bf16* Qp  = (bf16*)(ws + 24 * MB);
  bf16* Vp  = (bf16*)(ws + 32 * MB);
  bf16* Vtp = (bf16*)(ws + 40 * MB);
  bf16* Wtd = Abf;                                   // dead after gemm_proj
  float* PpA = (float*)(ws + 10 * MB);               // [32][8][128] (128KB)
  float* PpB = (float*)(ws + 10 * MB + 128 * 1024);  // (128KB)
  float* tot = (float*)(ws + 10 * MB + 256 * 1024);  // [32][64][64] (512KB)
  bf16* Suf = Vp;                                    // in-place over Vp
  float* PoA = (float*)d_out;                        // [32][8][128][64] (8MB)
  float* PoB = (float*)d_out + 2 * 1024 * 1024;      // (8MB)
  (void)in_sizes; (void)n_in; (void)out_size; (void)ws_size;

  // prep: cvt + QKV weight transpose + Wo transpose (merged)
  prep_kernel<<<3072, 256, 0, stream>>>(residual, Abf, Wk, Wq, Wv, Wkt, Wo, Wot);

  // QKV projections — 256x192 tiles, grid 256 (all CUs), queries pre-scaled
  gemm_proj_kernel<<<256, 512, 0, stream>>>(Abf, Wkt, Bk, Bq, Bv, Kp);

  // V-work: sufv column totals + V transpose (merged; both read Vp)
  vwork_kernel<<<3072, 256, 0, stream>>>(Vp, tot, Vtp);

  // in-place: Vp becomes Suf (bf16)
  sufv_scan_kernel<<<dim3(32, 64), 64, 0, stream>>>(Vp, tot);

  // attention: split-k, balanced (34 tiles per CU triple)
  attn_kernel<<<768, 256, 0, stream>>>(Qp, Kp, Vtp, Suf, Wtd, PoA, PoB, PpA, PpB);

  // combine halves for x >= 8
  combine_kernel<<<256, 256, 0, stream>>>(PoA, PoB, PpA, PpB, Suf, Wtd);

  // output projection -> fp32 d_out (overwrites PoA/PoB scratch)
  gemm_out_kernel<<<256, 256, 0, stream>>>(Wtd, Wot, Bo, outp);
}

// Round 14
// 148.479 us; speedup vs baseline: 1.0178x; 1.0178x over previous
//
#include <hip/hip_runtime.h>
#include <hip/hip_bf16.h>
#include <cmath>

typedef __bf16 bf16;
typedef __attribute__((ext_vector_type(4))) __bf16 bf16x4;
typedef __attribute__((ext_vector_type(8))) __bf16 bf16x8;
typedef __attribute__((ext_vector_type(4))) float f32x4;

#define B_ 2
#define S_ 2048
#define D_ 1024
#define N_ 16
#define H_ 64
// 0.125 * log2(e): folded into Q at projection so QK^T emits exp2-domain scores
#define QSCALE 0.18033688011112042f

__device__ __forceinline__ void gload16(const bf16* g, bf16* l) {
  __builtin_amdgcn_global_load_lds(
      (const __attribute__((address_space(1))) void*)(g),
      (__attribute__((address_space(3))) void*)(l), 16, 0, 0);
}

__device__ __forceinline__ f32x4 mfma16(bf16x8 a, bf16x8 b, f32x4 c) {
  return __builtin_amdgcn_mfma_f32_16x16x32_bf16(a, b, c, 0, 0, 0);
}

__device__ __forceinline__ f32x4 zero4() {
  f32x4 v = {0.0f, 0.0f, 0.0f, 0.0f};
  return v;
}

// ---------------------------------------------------------------------------
// Prep (merged, 3072 blocks x 256):
//   bi <  2048: residual fp32 -> bf16 (8 elems/thread)
//   2048..2815: QKV weight transpose, head z: [1024][64] fp32 -> [64][1024] bf16
//   2816..3071: Wo transpose: [1024][1024] fp32 -> bf16 transposed
// ---------------------------------------------------------------------------
__global__ __launch_bounds__(256) void prep_kernel(
    const float* __restrict__ residual, bf16* __restrict__ Abf,
    const float* __restrict__ Wk, const float* __restrict__ Wq,
    const float* __restrict__ Wv, bf16* __restrict__ Wkt,
    const float* __restrict__ Wo, bf16* __restrict__ Wot) {
  __shared__ bf16 t[64][72];
  const int bi = blockIdx.x;
  if (bi < 2048) {
    const int id = bi * 256 + threadIdx.x;
    const float4* p = (const float4*)(residual + (size_t)id * 8);
    float4 v0 = p[0], v1 = p[1];
    bf16x8 o;
    o[0] = (bf16)v0.x; o[1] = (bf16)v0.y; o[2] = (bf16)v0.z; o[3] = (bf16)v0.w;
    o[4] = (bf16)v1.x; o[5] = (bf16)v1.y; o[6] = (bf16)v1.z; o[7] = (bf16)v1.w;
    *(bf16x8*)(Abf + (size_t)id * 8) = o;
    return;
  }
  const float* ing; bf16* outg; int C, r0, c0;
  if (bi < 2816) {
    const int idx = bi - 2048, z = idx >> 4, xr = idx & 15;
    const float* W = (z < 16) ? Wk : (z < 32) ? Wq : Wv;
    ing = W + (size_t)(z & 15) * (1024 * 64);
    outg = Wkt + (size_t)z * (64 * 1024);
    C = 64; r0 = xr * 64; c0 = 0;
  } else {
    const int idx = bi - 2816, xr = idx & 15, yc = idx >> 4;
    ing = Wo; outg = Wot; C = 1024; r0 = xr * 64; c0 = yc * 64;
  }
  const int t8 = threadIdx.x & 7, trow = threadIdx.x >> 3;
#pragma unroll
  for (int p = 0; p < 2; ++p) {
    int r = trow + p * 32;
    const float4* src = (const float4*)(ing + (size_t)(r0 + r) * C + c0 + t8 * 8);
    float4 v0 = src[0], v1 = src[1];
    bf16x8 o;
    o[0] = (bf16)v0.x; o[1] = (bf16)v0.y; o[2] = (bf16)v0.z; o[3] = (bf16)v0.w;
    o[4] = (bf16)v1.x; o[5] = (bf16)v1.y; o[6] = (bf16)v1.z; o[7] = (bf16)v1.w;
    *(bf16x8*)(&t[r][t8 * 8]) = o;
  }
  __syncthreads();
#pragma unroll
  for (int p = 0; p < 2; ++p) {
    int c = trow + p * 32;
    bf16x8 v;
#pragma unroll
    for (int j = 0; j < 8; ++j) v[j] = t[t8 * 8 + j][c];
    *(bf16x8*)(outg + (size_t)(c0 + c) * 1024 + r0 + t8 * 8) = v;
  }
}

// ---------------------------------------------------------------------------
// V-work (merged, 3072 blocks x 256):
//   bi < 2048: sufv_tot — per-(hd, 32-row seg) column totals of Vp
//   else     : bf16 transpose Vp [S][H] -> Vtp [H][S] per head
// ---------------------------------------------------------------------------
__global__ __launch_bounds__(256) void vwork_kernel(
    const bf16* __restrict__ Vp, float* __restrict__ tot,
    bf16* __restrict__ Vtp) {
  __shared__ bf16 t[64][72];
  __shared__ float red[4][64];
  const int bi = blockIdx.x;
  if (bi < 2048) {
    const int hd = bi >> 6, seg = bi & 63;
    const int h = threadIdx.x & 63, sub = threadIdx.x >> 6;
    const bf16* Vh = Vp + (size_t)hd * S_ * H_;
    float a = 0.0f;
    const int k0 = seg * 32 + sub * 8;
#pragma unroll
    for (int k = 0; k < 8; ++k) a += (float)Vh[(size_t)(k0 + k) * H_ + h];
    red[sub][h] = a;
    __syncthreads();
    if (sub == 0)
      tot[(hd * 64 + seg) * 64 + h] = red[0][h] + red[1][h] + red[2][h] + red[3][h];
    return;
  }
  const int idx = bi - 2048, z = idx >> 5, xr = idx & 31;
  const bf16* ing = Vp + (size_t)z * (S_ * H_);
  bf16* outg = Vtp + (size_t)z * (S_ * H_);
  const int r0 = xr * 64;
  const int t8 = threadIdx.x & 7, trow = threadIdx.x >> 3;
#pragma unroll
  for (int p = 0; p < 2; ++p) {
    int r = trow + p * 32;
    bf16x8 v = *(const bf16x8*)(ing + (size_t)(r0 + r) * 64 + t8 * 8);
    *(bf16x8*)(&t[r][t8 * 8]) = v;
  }
  __syncthreads();
#pragma unroll
  for (int p = 0; p < 2; ++p) {
    int c = trow + p * 32;
    bf16x8 v;
#pragma unroll
    for (int j = 0; j < 8; ++j) v[j] = t[t8 * 8 + j][c];
    *(bf16x8*)(outg + (size_t)c * 2048 + r0 + t8 * 8) = v;
  }
}

// ---------------------------------------------------------------------------
// Suffix-V scan: Suf[hd][q][h] = sum_{k>q} V[hd][k][h], bf16 IN-PLACE over Vp.
// ---------------------------------------------------------------------------
__global__ __launch_bounds__(64) void sufv_scan_kernel(
    bf16* __restrict__ VS, const float* __restrict__ tot) {
  const int hd = blockIdx.x, seg = blockIdx.y, h = threadIdx.x;
  bf16* Vh = VS + (size_t)hd * S_ * H_;  // in: V, out: Suf (in-place)
  float a = 0.0f;
  for (int s2 = seg + 1; s2 < 64; ++s2) a += tot[(hd * 64 + s2) * 64 + h];
  for (int k = seg * 32 + 31; k >= seg * 32; --k) {
    const float v = (float)Vh[(size_t)k * H_ + h];  // read BEFORE overwrite
    Vh[(size_t)k * H_ + h] = (bf16)a;
    a += v;
  }
}

// ---------------------------------------------------------------------------
// QKV projection GEMM v2 (R11/R12-measured best: 256x256 tile, grid 192,
// 4-phase counted-vmcnt, XCD-remapped) + QSCALE on queries (for exp2 attn).
// R13's 256x192 variant staged 33% more bytes and was ~4 µs slower — reverted.
// ---------------------------------------------------------------------------
__global__ __launch_bounds__(512) void gemm_proj_kernel(
    const bf16* __restrict__ A, const bf16* __restrict__ Bt,
    const float* __restrict__ bk, const float* __restrict__ bq,
    const float* __restrict__ bv, bf16* __restrict__ proj_base) {
  __shared__ bf16 As[2][2][256 * 32];
  __shared__ bf16 Bs[2][2][256 * 32];
  const int tid = threadIdx.x;
  const int w = tid >> 6, l = tid & 63, lan = l & 15, grp = l >> 4;
  const int wm128 = (w >> 2) * 128, wn64 = (w & 3) * 64;
  const int bid = blockIdx.x;
  const int bid2 = (bid & 7) * 24 + (bid >> 3);  // XCD-contiguous remap
  const int m0 = (bid2 / 12) * 256, n0 = (bid2 % 12) * 256;
  const int zc = n0 >> 10;  // block-uniform (1024 % 256 == 0)
  const float* bias = (zc == 0) ? bk : (zc == 1 ? bq : bv);
  const float osc = (zc == 1) ? QSCALE : 1.0f;
  bf16* Out = proj_base + (size_t)zc * ((size_t)B_ * N_ * S_ * H_);
  const int posx = (grp ^ ((lan >> 1) & 3)) << 3;  // swizzled read chunk

#define STG(LDS_, GP_, rb_, buf_, kh_, kb_)                                    \
  do {                                                                         \
    _Pragma("unroll") for (int jj = 0; jj < 2; ++jj) {                         \
      const int ci = jj * 512 + tid;                                           \
      const int rw = ci >> 2, cp = ci & 3;                                     \
      const int gg = cp ^ ((rw >> 1) & 3);                                     \
      gload16(GP_ + (size_t)((rb_) + rw) * 1024 + (kb_) + (kh_) * 32 + gg * 8, \
              &LDS_[buf_][kh_][(jj * 512 + w * 64) * 8]);                      \
    }                                                                          \
  } while (0)

  f32x4 acc[8][4];
#pragma unroll
  for (int i = 0; i < 8; ++i)
#pragma unroll
    for (int jv = 0; jv < 4; ++jv) acc[i][jv] = zero4();

  bf16x8 b[4];

#define DO_PHASE(buf_, mq_, kk_, READB_)                                       \
  do {                                                                         \
    if (READB_) {                                                              \
      _Pragma("unroll") for (int nf = 0; nf < 4; ++nf)                         \
        b[nf] = *(const bf16x8*)(&Bs[buf_][kk_][(wn64 + nf * 16 + lan) * 32 + posx]); \
    }                                                                          \
    bf16x8 a[4];                                                               \
    _Pragma("unroll") for (int mf = 0; mf < 4; ++mf)                           \
      a[mf] = *(const bf16x8*)(&As[buf_][kk_][(wm128 + (mq_) * 64 + mf * 16 + lan) * 32 + posx]); \
    __builtin_amdgcn_s_setprio(1);                                             \
    _Pragma("unroll") for (int mf = 0; mf < 4; ++mf)                           \
      _Pragma("unroll") for (int nf = 0; nf < 4; ++nf)                         \
        acc[(mq_) * 4 + mf][nf] = mfma16(a[mf], b[nf], acc[(mq_) * 4 + mf][nf]); \
    __builtin_amdgcn_s_setprio(0);                                             \
  } while (0)

  // prologue: all 4 slots of K-step 0 into buf 0
  STG(As, A, m0, 0, 0, 0);
  STG(Bs, Bt, n0, 0, 0, 0);
  STG(As, A, m0, 0, 1, 0);
  STG(Bs, Bt, n0, 0, 1, 0);

  for (int t = 0; t < 15; ++t) {
    const int buf = t & 1;
    const int nkb = (t + 1) * 64;
    STG(As, A, m0, buf ^ 1, 0, nkb);
    asm volatile("s_waitcnt vmcnt(6)" ::: "memory");
    __builtin_amdgcn_s_barrier();
    asm volatile("" ::: "memory");
    DO_PHASE(buf, 0, 0, true);
    STG(Bs, Bt, n0, buf ^ 1, 0, nkb);
    asm volatile("" ::: "memory");
    __builtin_amdgcn_s_barrier();
    asm volatile("" ::: "memory");
    DO_PHASE(buf, 1, 0, false);
    STG(As, A, m0, buf ^ 1, 1, nkb);
    asm volatile("s_waitcnt vmcnt(6)" ::: "memory");
    __builtin_amdgcn_s_barrier();
    asm volatile("" ::: "memory");
    DO_PHASE(buf, 0, 1, true);
    STG(Bs, Bt, n0, buf ^ 1, 1, nkb);
    asm volatile("" ::: "memory");
    __builtin_amdgcn_s_barrier();
    asm volatile("" ::: "memory");
    DO_PHASE(buf, 1, 1, false);
  }
  {
    asm volatile("s_waitcnt vmcnt(4)" ::: "memory");
    __builtin_amdgcn_s_barrier();
    asm volatile("" ::: "memory");
    DO_PHASE(1, 0, 0, true);
    DO_PHASE(1, 1, 0, false);
    asm volatile("s_waitcnt vmcnt(0)" ::: "memory");
    __builtin_amdgcn_s_barrier();
    asm volatile("" ::: "memory");
    DO_PHASE(1, 0, 1, true);
    DO_PHASE(1, 1, 1, false);
  }
#undef STG
#undef DO_PHASE

  // epilogue: scatter to [z][b][n][s][h] + bias (+QSCALE for queries)
#pragma unroll
  for (int nf = 0; nf < 4; ++nf) {
    const int c10 = (n0 + wn64 + nf * 16 + lan) & 1023;
    const float bs = bias[c10];
    const int n = c10 >> 6, h = c10 & 63;
#pragma unroll
    for (int am = 0; am < 8; ++am) {
#pragma unroll
      for (int r = 0; r < 4; ++r) {
        const int m = m0 + wm128 + am * 16 + grp * 4 + r;
        const int bb = m >> 11, s = m & 2047;
        Out[((size_t)((bb * N_ + n) * S_ + s)) * H_ + h] = (bf16)((acc[am][nf][r] + bs) * osc);
      }
    }
  }
}

// ---------------------------------------------------------------------------
// Output projection GEMM (swizzled LDS, XCD-remapped): grid 256 (1D), 256 thr.
// ---------------------------------------------------------------------------
__global__ __launch_bounds__(256) void gemm_out_kernel(
    const bf16* __restrict__ A, const bf16* __restrict__ Bt,
    const float* __restrict__ bias, float* __restrict__ Out) {
  __shared__ bf16 As[128 * 64];
  __shared__ bf16 Bs[128 * 64];
  const int tid = threadIdx.x;
  const int w = tid >> 6, l = tid & 63, lan = l & 15, grp = l >> 4;
  const int mb = (w >> 1) * 64, nb = (w & 1) * 64;
  const int bid = blockIdx.x;
  const int bid2 = (bid & 7) * 32 + (bid >> 3);  // XCD-contiguous remap
  const int m0 = (bid2 >> 3) * 128, n0 = (bid2 & 7) * 128;
  const int lrow8 = l >> 3;
  const int swl = ((l & 7) ^ lrow8) * 8;
  const int l7 = lan & 7;

  f32x4 acc[4][4];
#pragma unroll
  for (int i = 0; i < 4; ++i)
#pragma unroll
    for (int j = 0; j < 4; ++j) acc[i][j] = zero4();

  for (int kb = 0; kb < 1024; kb += 64) {
    __syncthreads();
#pragma unroll
    for (int i = 0; i < 4; ++i) {
      int ch = w * 4 + i;
      gload16(A + (size_t)(m0 + ch * 8 + lrow8) * 1024 + kb + swl, As + ch * 512);
      gload16(Bt + (size_t)(n0 + ch * 8 + lrow8) * 1024 + kb + swl, Bs + ch * 512);
    }
    __syncthreads();
#pragma unroll
    for (int kk = 0; kk < 2; ++kk) {
      bf16x8 a[4], b[4];
#pragma unroll
      for (int mf = 0; mf < 4; ++mf)
        a[mf] = *(const bf16x8*)(As + (mb + mf * 16 + lan) * 64 + (((grp + kk * 4) ^ l7) << 3));
#pragma unroll
      for (int nf = 0; nf < 4; ++nf)
        b[nf] = *(const bf16x8*)(Bs + (nb + nf * 16 + lan) * 64 + (((grp + kk * 4) ^ l7) << 3));
#pragma unroll
      for (int mf = 0; mf < 4; ++mf)
#pragma unroll
        for (int nf = 0; nf < 4; ++nf)
          acc[mf][nf] = mfma16(a[mf], b[nf], acc[mf][nf]);
    }
  }
#pragma unroll
  for (int nf = 0; nf < 4; ++nf) {
    int c = n0 + nb + nf * 16 + lan;
    float bs = bias[c];
#pragma unroll
    for (int mf = 0; mf < 4; ++mf) {
#pragma unroll
      for (int r = 0; r < 4; ++r) {
        int m = m0 + mb + mf * 16 + grp * 4 + r;
        Out[(size_t)m * 1024 + c] = acc[mf][nf][r] + bs;
      }
    }
  }
}

// ---------------------------------------------------------------------------
// Attention — R7 structure + exp2-domain Q (R13-measured 49.5 µs). Split-k:
//   quarter 0 (bi<256):  x=15-wv, k-tiles [0, x+1)     -> fp32 partial A
//   quarter 1 (bi<512):  x=15-wv, k-tiles [x+1, 2x+2)  -> fp32 partial B
//   quarter 2 (bi<768):  x=wv,    k-tiles [0, 2x+2)    -> final Wtd rows
// grid 768, block 256 (4 waves x 32 q-rows). Suf is bf16.
// ---------------------------------------------------------------------------
__global__ __launch_bounds__(256) void attn_kernel(
    const bf16* __restrict__ Qp, const bf16* __restrict__ Kp,
    const bf16* __restrict__ Vt, const bf16* __restrict__ Suf,
    bf16* __restrict__ Wtd, float* __restrict__ PoA, float* __restrict__ PoB,
    float* __restrict__ PpA, float* __restrict__ PpB) {
  __shared__ bf16 Ks[2][64 * 64];
  __shared__ bf16 Vs[2][64 * 64];
  __shared__ bf16 Ps[4][32 * 72];
  const int tid = threadIdx.x;
  const int w = tid >> 6, l = tid & 63, lan = l & 15, grp = l >> 4;
  const int bi = blockIdx.x;
  const int qq = bi >> 8;
  const int j = bi & 255;
  const int hd = j & 31, wv = j >> 5;
  int x, t0, t1;
  if (qq == 0)      { x = 15 - wv; t0 = 0;     t1 = x + 1; }
  else if (qq == 1) { x = 15 - wv; t0 = x + 1; t1 = 2 * x + 2; }
  else              { x = wv;      t0 = 0;     t1 = 2 * x + 2; }
  const int qw = x * 128 + w * 32;
  const bf16* Qh = Qp + (size_t)hd * S_ * H_;
  const bf16* Kh = Kp + (size_t)hd * S_ * H_;
  const bf16* Vh = Vt + (size_t)hd * H_ * S_;
  const bf16* Sufh = Suf + (size_t)hd * S_ * H_;
  const int lrow8 = l >> 3;
  const int swl = ((l & 7) ^ lrow8) * 8;
  const int l7 = lan & 7;

#define STAGE(buf, kb_)                                                        \
  do {                                                                         \
    _Pragma("unroll") for (int i2 = 0; i2 < 2; ++i2) {                         \
      int ch = w * 2 + i2;                                                     \
      gload16(Kh + (size_t)((kb_) + ch * 8 + lrow8) * H_ + swl,                \
              &Ks[buf][ch * 512]);                                             \
      gload16(Vh + (size_t)(ch * 8 + lrow8) * S_ + (kb_) + swl,                \
              &Vs[buf][ch * 512]);                                             \
    }                                                                          \
  } while (0)

  // Q fragments (B-operand for swapped QK^T: n=lan=q, k=grp*8+j (+32*kf))
  bf16x8 qa[2][2];
#pragma unroll
  for (int qt = 0; qt < 2; ++qt)
#pragma unroll
    for (int kf = 0; kf < 2; ++kf)
      qa[qt][kf] = *(const bf16x8*)(Qh + (size_t)(qw + qt * 16 + lan) * H_ + grp * 8 + kf * 32);

  f32x4 o[2][4];
  float psum[2] = {0.0f, 0.0f};
#pragma unroll
  for (int qt = 0; qt < 2; ++qt)
#pragma unroll
    for (int hf = 0; hf < 4; ++hf) o[qt][hf] = zero4();

  bf16* Pw = &Ps[w][0];

  STAGE(0, t0 * 64);
  for (int tt = t0; tt < t1; ++tt) {
    const int kb = tt * 64;
    const int cur = (tt - t0) & 1;
    if (tt + 1 < t1) {
      STAGE(cur ^ 1, kb + 64);
      asm volatile("s_waitcnt vmcnt(4)" ::: "memory");
    } else {
      asm volatile("s_waitcnt vmcnt(0)" ::: "memory");
    }
    __builtin_amdgcn_s_barrier();

    if (kb <= qw + 31) {
      const bf16* Kc = &Ks[cur][0];
      const bf16* Vc = &Vs[cur][0];

      // --- swapped QK^T: s2[k2][qt], col=lan=q, row=grp*4+r=k ---
      f32x4 s2[4][2];
#pragma unroll
      for (int k2 = 0; k2 < 4; ++k2)
#pragma unroll
        for (int qt = 0; qt < 2; ++qt) s2[k2][qt] = zero4();
      __builtin_amdgcn_s_setprio(1);
#pragma unroll
      for (int kf = 0; kf < 2; ++kf) {
        bf16x8 kfr[4];
#pragma unroll
        for (int k2 = 0; k2 < 4; ++k2)
          kfr[k2] = *(const bf16x8*)(Kc + (k2 * 16 + lan) * 64 + (((grp + kf * 4) ^ l7) << 3));
#pragma unroll
        for (int k2 = 0; k2 < 4; ++k2)
#pragma unroll
          for (int qt = 0; qt < 2; ++qt)
            s2[k2][qt] = mfma16(kfr[k2], qa[qt][kf], s2[k2][qt]);
      }
      __builtin_amdgcn_s_setprio(0);

      // --- p = exp2(s) (Q pre-scaled), diag-mask, psum, pack -> b64 write ---
      const bool maskt = (kb + 63 > qw);
#pragma unroll
      for (int qt = 0; qt < 2; ++qt) {
        const int q_g = qw + qt * 16 + lan;
#pragma unroll
        for (int k2 = 0; k2 < 4; ++k2) {
          f32x4 p;
#pragma unroll
          for (int r = 0; r < 4; ++r) p[r] = exp2f(s2[k2][qt][r]);
          if (maskt) {
            const int kg0 = kb + k2 * 16 + grp * 4;
#pragma unroll
            for (int r = 0; r < 4; ++r)
              if (kg0 + r > q_g) p[r] = 0.0f;
          }
          psum[qt] += (p[0] + p[1]) + (p[2] + p[3]);
          unsigned plo, phi;
          asm("v_cvt_pk_bf16_f32 %0, %1, %2" : "=v"(plo) : "v"(p[0]), "v"(p[1]));
          asm("v_cvt_pk_bf16_f32 %0, %1, %2" : "=v"(phi) : "v"(p[2]), "v"(p[3]));
          uint2 u; u.x = plo; u.y = phi;
          *(uint2*)(Pw + (qt * 16 + lan) * 72 + k2 * 16 + grp * 4) = u;
        }
      }

      // --- PV ---
      __builtin_amdgcn_s_setprio(1);
#pragma unroll
      for (int ks = 0; ks < 2; ++ks) {
        bf16x8 pa[2], vb[4];
#pragma unroll
        for (int qt = 0; qt < 2; ++qt)
          pa[qt] = *(const bf16x8*)(Pw + (qt * 16 + lan) * 72 + grp * 8 + ks * 32);
#pragma unroll
        for (int hf = 0; hf < 4; ++hf)
          vb[hf] = *(const bf16x8*)(Vc + (hf * 16 + lan) * 64 + (((grp + ks * 4) ^ l7) << 3));
#pragma unroll
        for (int qt = 0; qt < 2; ++qt)
#pragma unroll
          for (int hf = 0; hf < 4; ++hf)
            o[qt][hf] = mfma16(pa[qt], vb[hf], o[qt][hf]);
      }
      __builtin_amdgcn_s_setprio(0);
    }
    __builtin_amdgcn_s_barrier();
  }
#undef STAGE

  // psum: reduce over grp (lanes sharing lan); q = qt*16+lan
#pragma unroll
  for (int qt = 0; qt < 2; ++qt) {
    psum[qt] += __shfl_xor(psum[qt], 16);
    psum[qt] += __shfl_xor(psum[qt], 32);
  }

  if (qq == 2) {
    // final: o = (o_causal + SufV) / (psum + (2047-q))
    const size_t outbase = (size_t)(hd >> 4) * S_ * (N_ * H_) + (size_t)(hd & 15) * H_;
#pragma unroll
    for (int qt = 0; qt < 2; ++qt) {
#pragma unroll
      for (int r = 0; r < 4; ++r) {
        const int q_g = qw + qt * 16 + grp * 4 + r;
        const float ps = __shfl(psum[qt], grp * 4 + r);
        const float inv = 1.0f / (ps + (float)(2047 - q_g));
#pragma unroll
        for (int hf = 0; hf < 4; ++hf) {
          const int h = hf * 16 + lan;
          const float suf = (float)Sufh[(size_t)q_g * H_ + h];
          Wtd[outbase + (size_t)q_g * (N_ * H_) + h] = (bf16)((o[qt][hf][r] + suf) * inv);
        }
      }
    }
  } else {
    // partial: raw fp32 o + row psums
    float* Po = (qq == 0) ? PoA : PoB;
    float* Pp = (qq == 0) ? PpA : PpB;
    const int pb = (hd * 8 + (x - 8)) * 128 + w * 32;
#pragma unroll
    for (int qt = 0; qt < 2; ++qt) {
#pragma unroll
      for (int r = 0; r < 4; ++r) {
        const int rl = qt * 16 + grp * 4 + r;
        const float ps = __shfl(psum[qt], grp * 4 + r);
        if (lan == 0) Pp[pb + rl] = ps;
#pragma unroll
        for (int hf = 0; hf < 4; ++hf)
          Po[(size_t)(pb + rl) * 64 + hf * 16 + lan] = o[qt][hf][r];
      }
    }
  }
}

// ---------------------------------------------------------------------------
// Combine: for x in 8..15, Wtd = (PoA + PoB + Suf) / (PpA + PpB + 2047-q).
// ---------------------------------------------------------------------------
__global__ __launch_bounds__(256) void combine_kernel(
    const float* __restrict__ PoA, const float* __restrict__ PoB,
    const float* __restrict__ PpA, const float* __restrict__ PpB,
    const bf16* __restrict__ Suf, bf16* __restrict__ Wtd) {
  const int hd = blockIdx.x >> 3, xi = blockIdx.x & 7;
  const int x = xi + 8;
  const int pb = (hd * 8 + xi) * 128;
  const size_t outbase = (size_t)(hd >> 4) * S_ * (N_ * H_) + (size_t)(hd & 15) * H_;
#pragma unroll
  for (int it = 0; it < 8; ++it) {
    const int e = it * 256 + threadIdx.x;  // 0..2047 float4 units
    const int rl = e >> 4, h4 = (e & 15) * 4;
    const int q_g = x * 128 + rl;
    const float Z = PpA[pb + rl] + PpB[pb + rl] + (float)(2047 - q_g);
    const float inv = 1.0f / Z;
    const float4 a = *(const float4*)(PoA + (size_t)(pb + rl) * 64 + h4);
    const float4 b = *(const float4*)(PoB + (size_t)(pb + rl) * 64 + h4);
    const bf16x4 s4 = *(const bf16x4*)(Suf + ((size_t)hd * S_ + q_g) * 64 + h4);
    bf16x4 ov;
    ov[0] = (bf16)((a.x + b.x + (float)s4[0]) * inv);
    ov[1] = (bf16)((a.y + b.y + (float)s4[1]) * inv);
    ov[2] = (bf16)((a.z + b.z + (float)s4[2]) * inv);
    ov[3] = (bf16)((a.w + b.w + (float)s4[3]) * inv);
    *(bf16x4*)(Wtd + outbase + (size_t)q_g * (N_ * H_) + h4) = ov;
  }
}

// ---------------------------------------------------------------------------
extern "C" void kernel_launch(void* const* d_in, const int* in_sizes, int n_in,
                              void* d_out, int out_size, void* d_ws, size_t ws_size,
                              hipStream_t stream) {
  const float* residual = (const float*)d_in[0];
  const float* Wk = (const float*)d_in[1];
  const float* Wq = (const float*)d_in[2];
  const float* Wv = (const float*)d_in[3];
  const float* Wo = (const float*)d_in[4];
  const float* Bk = (const float*)d_in[5];
  const float* Bq = (const float*)d_in[6];
  const float* Bv = (const float*)d_in[7];
  const float* Bo = (const float*)d_in[8];
  float* outp = (float*)d_out;

  // ws layout (peak 48MB — proven safe; do NOT exceed):
  //   [ 0.. 8) Abf (prep out, gemm_proj A)       -> Wtd (attn/combine out)
  //   [ 8..10) Wot (live to end)
  //   [10..16) Wkt (gemm_proj B, [3072][1024])   -> PpA, PpB, tot
  //   [16..24) Kp   [24..32) Qp
  //   [32..40) Vp (proj V) -> in-place Suf (bf16) via sufv_scan
  //   [40..48) Vtp
  // d_out (16MB fp32): PoA [0..8MB) + PoB [8..16MB) until gemm_out overwrites.
  char* ws = (char*)d_ws;
  const size_t MB = 1024 * 1024;
  bf16* Abf = (bf16*)(ws + 0 * MB);
  bf16* Wot = (bf16*)(ws + 8 * MB);
  bf16* Wkt = (bf16*)(ws + 10 * MB);
  bf16* Kp  = (bf16*)(ws + 16 * MB);
  bf16* Qp  = (bf16*)(ws + 24 * MB);
  bf16* Vp  = (bf16*)(ws + 32 * MB);
  bf16* Vtp = (bf16*)(ws + 40 * MB);
  bf16* Wtd = Abf;                                   // dead after gemm_proj
  float* PpA = (float*)(ws + 10 * MB);               // [32][8][128] (128KB)
  float* PpB = (float*)(ws + 10 * MB + 128 * 1024);  // (128KB)
  float* tot = (float*)(ws + 10 * MB + 256 * 1024);  // [32][64][64] (512KB)
  bf16* Suf = Vp;                                    // in-place over Vp
  float* PoA = (float*)d_out;                        // [32][8][128][64] (8MB)
  float* PoB = (float*)d_out + 2 * 1024 * 1024;      // (8MB)
  (void)in_sizes; (void)n_in; (void)out_size; (void)ws_size;

  // prep: cvt + QKV weight transpose + Wo transpose (merged)
  prep_kernel<<<3072, 256, 0, stream>>>(residual, Abf, Wk, Wq, Wv, Wkt, Wo, Wot);

  // QKV projections — 256² tiles, grid 192 (R12-measured best), Q pre-scaled
  gemm_proj_kernel<<<192, 512, 0, stream>>>(Abf, Wkt, Bk, Bq, Bv, Kp);

  // V-work: sufv column totals + V transpose (merged; both read Vp)
  vwork_kernel<<<3072, 256, 0, stream>>>(Vp, tot, Vtp);

  // in-place: Vp becomes Suf (bf16)
  sufv_scan_kernel<<<dim3(32, 64), 64, 0, stream>>>(Vp, tot);

  // attention: split-k, balanced (34 tiles per CU triple)
  attn_kernel<<<768, 256, 0, stream>>>(Qp, Kp, Vtp, Suf, Wtd, PoA, PoB, PpA, PpB);

  // combine halves for x >= 8
  combine_kernel<<<256, 256, 0, stream>>>(PoA, PoB, PpA, PpB, Suf, Wtd);

  // output projection -> fp32 d_out (overwrites PoA/PoB scratch)
  gemm_out_kernel<<<256, 256, 0, stream>>>(Wtd, Wot, Bo, outp);
}

// Round 15
// 142.906 us; speedup vs baseline: 1.0575x; 1.0390x over previous
//
#include <hip/hip_runtime.h>
#include <hip/hip_bf16.h>
#include <cmath>

typedef __bf16 bf16;
typedef __attribute__((ext_vector_type(4))) __bf16 bf16x4;
typedef __attribute__((ext_vector_type(8))) __bf16 bf16x8;
typedef __attribute__((ext_vector_type(4))) float f32x4;

#define B_ 2
#define S_ 2048
#define D_ 1024
#define N_ 16
#define H_ 64
// 0.125 * log2(e): folded into Q at projection so QK^T emits exp2-domain scores
#define QSCALE 0.18033688011112042f

__device__ __forceinline__ void gload16(const bf16* g, bf16* l) {
  __builtin_amdgcn_global_load_lds(
      (const __attribute__((address_space(1))) void*)(g),
      (__attribute__((address_space(3))) void*)(l), 16, 0, 0);
}

__device__ __forceinline__ f32x4 mfma16(bf16x8 a, bf16x8 b, f32x4 c) {
  return __builtin_amdgcn_mfma_f32_16x16x32_bf16(a, b, c, 0, 0, 0);
}

__device__ __forceinline__ f32x4 zero4() {
  f32x4 v = {0.0f, 0.0f, 0.0f, 0.0f};
  return v;
}

// ---------------------------------------------------------------------------
// Prep (merged, 3072 blocks x 256):
//   bi <  2048: residual fp32 -> bf16 (8 elems/thread)
//   2048..2815: QKV weight transpose, head z: [1024][64] fp32 -> [64][1024] bf16
//   2816..3071: Wo transpose: [1024][1024] fp32 -> bf16 transposed
// ---------------------------------------------------------------------------
__global__ __launch_bounds__(256) void prep_kernel(
    const float* __restrict__ residual, bf16* __restrict__ Abf,
    const float* __restrict__ Wk, const float* __restrict__ Wq,
    const float* __restrict__ Wv, bf16* __restrict__ Wkt,
    const float* __restrict__ Wo, bf16* __restrict__ Wot) {
  __shared__ bf16 t[64][72];
  const int bi = blockIdx.x;
  if (bi < 2048) {
    const int id = bi * 256 + threadIdx.x;
    const float4* p = (const float4*)(residual + (size_t)id * 8);
    float4 v0 = p[0], v1 = p[1];
    bf16x8 o;
    o[0] = (bf16)v0.x; o[1] = (bf16)v0.y; o[2] = (bf16)v0.z; o[3] = (bf16)v0.w;
    o[4] = (bf16)v1.x; o[5] = (bf16)v1.y; o[6] = (bf16)v1.z; o[7] = (bf16)v1.w;
    *(bf16x8*)(Abf + (size_t)id * 8) = o;
    return;
  }
  const float* ing; bf16* outg; int C, r0, c0;
  if (bi < 2816) {
    const int idx = bi - 2048, z = idx >> 4, xr = idx & 15;
    const float* W = (z < 16) ? Wk : (z < 32) ? Wq : Wv;
    ing = W + (size_t)(z & 15) * (1024 * 64);
    outg = Wkt + (size_t)z * (64 * 1024);
    C = 64; r0 = xr * 64; c0 = 0;
  } else {
    const int idx = bi - 2816, xr = idx & 15, yc = idx >> 4;
    ing = Wo; outg = Wot; C = 1024; r0 = xr * 64; c0 = yc * 64;
  }
  const int t8 = threadIdx.x & 7, trow = threadIdx.x >> 3;
#pragma unroll
  for (int p = 0; p < 2; ++p) {
    int r = trow + p * 32;
    const float4* src = (const float4*)(ing + (size_t)(r0 + r) * C + c0 + t8 * 8);
    float4 v0 = src[0], v1 = src[1];
    bf16x8 o;
    o[0] = (bf16)v0.x; o[1] = (bf16)v0.y; o[2] = (bf16)v0.z; o[3] = (bf16)v0.w;
    o[4] = (bf16)v1.x; o[5] = (bf16)v1.y; o[6] = (bf16)v1.z; o[7] = (bf16)v1.w;
    *(bf16x8*)(&t[r][t8 * 8]) = o;
  }
  __syncthreads();
#pragma unroll
  for (int p = 0; p < 2; ++p) {
    int c = trow + p * 32;
    bf16x8 v;
#pragma unroll
    for (int j = 0; j < 8; ++j) v[j] = t[t8 * 8 + j][c];
    *(bf16x8*)(outg + (size_t)(c0 + c) * 1024 + r0 + t8 * 8) = v;
  }
}

// ---------------------------------------------------------------------------
// V-work (merged, 3072 blocks x 256):
//   bi < 2048: sufv_tot — per-(hd, 32-row seg) column totals of Vp
//   else     : bf16 transpose Vp [S][H] -> Vtp [H][S] per head
// ---------------------------------------------------------------------------
__global__ __launch_bounds__(256) void vwork_kernel(
    const bf16* __restrict__ Vp, float* __restrict__ tot,
    bf16* __restrict__ Vtp) {
  __shared__ bf16 t[64][72];
  __shared__ float red[4][64];
  const int bi = blockIdx.x;
  if (bi < 2048) {
    const int hd = bi >> 6, seg = bi & 63;
    const int h = threadIdx.x & 63, sub = threadIdx.x >> 6;
    const bf16* Vh = Vp + (size_t)hd * S_ * H_;
    float a = 0.0f;
    const int k0 = seg * 32 + sub * 8;
#pragma unroll
    for (int k = 0; k < 8; ++k) a += (float)Vh[(size_t)(k0 + k) * H_ + h];
    red[sub][h] = a;
    __syncthreads();
    if (sub == 0)
      tot[(hd * 64 + seg) * 64 + h] = red[0][h] + red[1][h] + red[2][h] + red[3][h];
    return;
  }
  const int idx = bi - 2048, z = idx >> 5, xr = idx & 31;
  const bf16* ing = Vp + (size_t)z * (S_ * H_);
  bf16* outg = Vtp + (size_t)z * (S_ * H_);
  const int r0 = xr * 64;
  const int t8 = threadIdx.x & 7, trow = threadIdx.x >> 3;
#pragma unroll
  for (int p = 0; p < 2; ++p) {
    int r = trow + p * 32;
    bf16x8 v = *(const bf16x8*)(ing + (size_t)(r0 + r) * 64 + t8 * 8);
    *(bf16x8*)(&t[r][t8 * 8]) = v;
  }
  __syncthreads();
#pragma unroll
  for (int p = 0; p < 2; ++p) {
    int c = trow + p * 32;
    bf16x8 v;
#pragma unroll
    for (int j = 0; j < 8; ++j) v[j] = t[t8 * 8 + j][c];
    *(bf16x8*)(outg + (size_t)c * 2048 + r0 + t8 * 8) = v;
  }
}

// ---------------------------------------------------------------------------
// Suffix-V scan: Suf[hd][q][h] = sum_{k>q} V[hd][k][h], bf16 IN-PLACE over Vp.
// ---------------------------------------------------------------------------
__global__ __launch_bounds__(64) void sufv_scan_kernel(
    bf16* __restrict__ VS, const float* __restrict__ tot) {
  const int hd = blockIdx.x, seg = blockIdx.y, h = threadIdx.x;
  bf16* Vh = VS + (size_t)hd * S_ * H_;  // in: V, out: Suf (in-place)
  float a = 0.0f;
  for (int s2 = seg + 1; s2 < 64; ++s2) a += tot[(hd * 64 + s2) * 64 + h];
  for (int k = seg * 32 + 31; k >= seg * 32; --k) {
    const float v = (float)Vh[(size_t)k * H_ + h];  // read BEFORE overwrite
    Vh[(size_t)k * H_ + h] = (bf16)a;
    a += v;
  }
}

// ---------------------------------------------------------------------------
// QKV projection GEMM v2 (R11/R12-measured best: 256x256 tile, grid 192,
// 4-phase counted-vmcnt, XCD-remapped) + QSCALE on queries (for exp2 attn).
// ---------------------------------------------------------------------------
__global__ __launch_bounds__(512) void gemm_proj_kernel(
    const bf16* __restrict__ A, const bf16* __restrict__ Bt,
    const float* __restrict__ bk, const float* __restrict__ bq,
    const float* __restrict__ bv, bf16* __restrict__ proj_base) {
  __shared__ bf16 As[2][2][256 * 32];
  __shared__ bf16 Bs[2][2][256 * 32];
  const int tid = threadIdx.x;
  const int w = tid >> 6, l = tid & 63, lan = l & 15, grp = l >> 4;
  const int wm128 = (w >> 2) * 128, wn64 = (w & 3) * 64;
  const int bid = blockIdx.x;
  const int bid2 = (bid & 7) * 24 + (bid >> 3);  // XCD-contiguous remap
  const int m0 = (bid2 / 12) * 256, n0 = (bid2 % 12) * 256;
  const int zc = n0 >> 10;  // block-uniform (1024 % 256 == 0)
  const float* bias = (zc == 0) ? bk : (zc == 1 ? bq : bv);
  const float osc = (zc == 1) ? QSCALE : 1.0f;
  bf16* Out = proj_base + (size_t)zc * ((size_t)B_ * N_ * S_ * H_);
  const int posx = (grp ^ ((lan >> 1) & 3)) << 3;  // swizzled read chunk

#define STG(LDS_, GP_, rb_, buf_, kh_, kb_)                                    \
  do {                                                                         \
    _Pragma("unroll") for (int jj = 0; jj < 2; ++jj) {                         \
      const int ci = jj * 512 + tid;                                           \
      const int rw = ci >> 2, cp = ci & 3;                                     \
      const int gg = cp ^ ((rw >> 1) & 3);                                     \
      gload16(GP_ + (size_t)((rb_) + rw) * 1024 + (kb_) + (kh_) * 32 + gg * 8, \
              &LDS_[buf_][kh_][(jj * 512 + w * 64) * 8]);                      \
    }                                                                          \
  } while (0)

  f32x4 acc[8][4];
#pragma unroll
  for (int i = 0; i < 8; ++i)
#pragma unroll
    for (int jv = 0; jv < 4; ++jv) acc[i][jv] = zero4();

  bf16x8 b[4];

#define DO_PHASE(buf_, mq_, kk_, READB_)                                       \
  do {                                                                         \
    if (READB_) {                                                              \
      _Pragma("unroll") for (int nf = 0; nf < 4; ++nf)                         \
        b[nf] = *(const bf16x8*)(&Bs[buf_][kk_][(wn64 + nf * 16 + lan) * 32 + posx]); \
    }                                                                          \
    bf16x8 a[4];                                                               \
    _Pragma("unroll") for (int mf = 0; mf < 4; ++mf)                           \
      a[mf] = *(const bf16x8*)(&As[buf_][kk_][(wm128 + (mq_) * 64 + mf * 16 + lan) * 32 + posx]); \
    __builtin_amdgcn_s_setprio(1);                                             \
    _Pragma("unroll") for (int mf = 0; mf < 4; ++mf)                           \
      _Pragma("unroll") for (int nf = 0; nf < 4; ++nf)                         \
        acc[(mq_) * 4 + mf][nf] = mfma16(a[mf], b[nf], acc[(mq_) * 4 + mf][nf]); \
    __builtin_amdgcn_s_setprio(0);                                             \
  } while (0)

  // prologue: all 4 slots of K-step 0 into buf 0
  STG(As, A, m0, 0, 0, 0);
  STG(Bs, Bt, n0, 0, 0, 0);
  STG(As, A, m0, 0, 1, 0);
  STG(Bs, Bt, n0, 0, 1, 0);

  for (int t = 0; t < 15; ++t) {
    const int buf = t & 1;
    const int nkb = (t + 1) * 64;
    STG(As, A, m0, buf ^ 1, 0, nkb);
    asm volatile("s_waitcnt vmcnt(6)" ::: "memory");
    __builtin_amdgcn_s_barrier();
    asm volatile("" ::: "memory");
    DO_PHASE(buf, 0, 0, true);
    STG(Bs, Bt, n0, buf ^ 1, 0, nkb);
    asm volatile("" ::: "memory");
    __builtin_amdgcn_s_barrier();
    asm volatile("" ::: "memory");
    DO_PHASE(buf, 1, 0, false);
    STG(As, A, m0, buf ^ 1, 1, nkb);
    asm volatile("s_waitcnt vmcnt(6)" ::: "memory");
    __builtin_amdgcn_s_barrier();
    asm volatile("" ::: "memory");
    DO_PHASE(buf, 0, 1, true);
    STG(Bs, Bt, n0, buf ^ 1, 1, nkb);
    asm volatile("" ::: "memory");
    __builtin_amdgcn_s_barrier();
    asm volatile("" ::: "memory");
    DO_PHASE(buf, 1, 1, false);
  }
  {
    asm volatile("s_waitcnt vmcnt(4)" ::: "memory");
    __builtin_amdgcn_s_barrier();
    asm volatile("" ::: "memory");
    DO_PHASE(1, 0, 0, true);
    DO_PHASE(1, 1, 0, false);
    asm volatile("s_waitcnt vmcnt(0)" ::: "memory");
    __builtin_amdgcn_s_barrier();
    asm volatile("" ::: "memory");
    DO_PHASE(1, 0, 1, true);
    DO_PHASE(1, 1, 1, false);
  }
#undef STG
#undef DO_PHASE

  // epilogue: scatter to [z][b][n][s][h] + bias (+QSCALE for queries)
#pragma unroll
  for (int nf = 0; nf < 4; ++nf) {
    const int c10 = (n0 + wn64 + nf * 16 + lan) & 1023;
    const float bs = bias[c10];
    const int n = c10 >> 6, h = c10 & 63;
#pragma unroll
    for (int am = 0; am < 8; ++am) {
#pragma unroll
      for (int r = 0; r < 4; ++r) {
        const int m = m0 + wm128 + am * 16 + grp * 4 + r;
        const int bb = m >> 11, s = m & 2047;
        Out[((size_t)((bb * N_ + n) * S_ + s)) * H_ + h] = (bf16)((acc[am][nf][r] + bs) * osc);
      }
    }
  }
}

// ---------------------------------------------------------------------------
// Output projection GEMM v2: 128x64 tiles -> grid 512 = 2 blocks/CU (v1's
// grid 256 = 1 block/CU, 1 wave/SIMD had zero latency hiding; m114 cross-
// block overlap needs >=2 resident blocks). B traffic doubles but Wot (2MB)
// is L2-resident. Per-wave 64x32 output, acc[4][2]. Same math per element.
// ---------------------------------------------------------------------------
__global__ __launch_bounds__(256) void gemm_out_kernel(
    const bf16* __restrict__ A, const bf16* __restrict__ Bt,
    const float* __restrict__ bias, float* __restrict__ Out) {
  __shared__ bf16 As[128 * 64];
  __shared__ bf16 Bs[64 * 64];
  const int tid = threadIdx.x;
  const int w = tid >> 6, l = tid & 63, lan = l & 15, grp = l >> 4;
  const int mb = (w >> 1) * 64, nb = (w & 1) * 32;
  const int bid = blockIdx.x;
  const int bid2 = (bid & 7) * 64 + (bid >> 3);  // XCD-contiguous remap
  const int m0 = (bid2 >> 4) * 128, n0 = (bid2 & 15) * 64;
  const int lrow8 = l >> 3;
  const int swl = ((l & 7) ^ lrow8) * 8;
  const int l7 = lan & 7;

  f32x4 acc[4][2];
#pragma unroll
  for (int i = 0; i < 4; ++i)
#pragma unroll
    for (int j = 0; j < 2; ++j) acc[i][j] = zero4();

  for (int kb = 0; kb < 1024; kb += 64) {
    __syncthreads();
#pragma unroll
    for (int i = 0; i < 4; ++i) {
      int ch = w * 4 + i;
      gload16(A + (size_t)(m0 + ch * 8 + lrow8) * 1024 + kb + swl, As + ch * 512);
    }
#pragma unroll
    for (int i = 0; i < 2; ++i) {
      int ch = w * 2 + i;
      gload16(Bt + (size_t)(n0 + ch * 8 + lrow8) * 1024 + kb + swl, Bs + ch * 512);
    }
    __syncthreads();
#pragma unroll
    for (int kk = 0; kk < 2; ++kk) {
      bf16x8 a[4], b[2];
#pragma unroll
      for (int mf = 0; mf < 4; ++mf)
        a[mf] = *(const bf16x8*)(As + (mb + mf * 16 + lan) * 64 + (((grp + kk * 4) ^ l7) << 3));
#pragma unroll
      for (int nf = 0; nf < 2; ++nf)
        b[nf] = *(const bf16x8*)(Bs + (nb + nf * 16 + lan) * 64 + (((grp + kk * 4) ^ l7) << 3));
#pragma unroll
      for (int mf = 0; mf < 4; ++mf)
#pragma unroll
        for (int nf = 0; nf < 2; ++nf)
          acc[mf][nf] = mfma16(a[mf], b[nf], acc[mf][nf]);
    }
  }
#pragma unroll
  for (int nf = 0; nf < 2; ++nf) {
    int c = n0 + nb + nf * 16 + lan;
    float bs = bias[c];
#pragma unroll
    for (int mf = 0; mf < 4; ++mf) {
#pragma unroll
      for (int r = 0; r < 4; ++r) {
        int m = m0 + mb + mf * 16 + grp * 4 + r;
        Out[(size_t)m * 1024 + c] = acc[mf][nf][r] + bs;
      }
    }
  }
}

// ---------------------------------------------------------------------------
// Attention — R7 structure + exp2-domain Q (R13/R14-measured ~50 µs). Split-k:
//   quarter 0 (bi<256):  x=15-wv, k-tiles [0, x+1)     -> fp32 partial A
//   quarter 1 (bi<512):  x=15-wv, k-tiles [x+1, 2x+2)  -> fp32 partial B
//   quarter 2 (bi<768):  x=wv,    k-tiles [0, 2x+2)    -> final Wtd rows
// grid 768, block 256 (4 waves x 32 q-rows). Suf is bf16.
// ---------------------------------------------------------------------------
__global__ __launch_bounds__(256) void attn_kernel(
    const bf16* __restrict__ Qp, const bf16* __restrict__ Kp,
    const bf16* __restrict__ Vt, const bf16* __restrict__ Suf,
    bf16* __restrict__ Wtd, float* __restrict__ PoA, float* __restrict__ PoB,
    float* __restrict__ PpA, float* __restrict__ PpB) {
  __shared__ bf16 Ks[2][64 * 64];
  __shared__ bf16 Vs[2][64 * 64];
  __shared__ bf16 Ps[4][32 * 72];
  const int tid = threadIdx.x;
  const int w = tid >> 6, l = tid & 63, lan = l & 15, grp = l >> 4;
  const int bi = blockIdx.x;
  const int qq = bi >> 8;
  const int j = bi & 255;
  const int hd = j & 31, wv = j >> 5;
  int x, t0, t1;
  if (qq == 0)      { x = 15 - wv; t0 = 0;     t1 = x + 1; }
  else if (qq == 1) { x = 15 - wv; t0 = x + 1; t1 = 2 * x + 2; }
  else              { x = wv;      t0 = 0;     t1 = 2 * x + 2; }
  const int qw = x * 128 + w * 32;
  const bf16* Qh = Qp + (size_t)hd * S_ * H_;
  const bf16* Kh = Kp + (size_t)hd * S_ * H_;
  const bf16* Vh = Vt + (size_t)hd * H_ * S_;
  const bf16* Sufh = Suf + (size_t)hd * S_ * H_;
  const int lrow8 = l >> 3;
  const int swl = ((l & 7) ^ lrow8) * 8;
  const int l7 = lan & 7;

#define STAGE(buf, kb_)                                                        \
  do {                                                                         \
    _Pragma("unroll") for (int i2 = 0; i2 < 2; ++i2) {                         \
      int ch = w * 2 + i2;                                                     \
      gload16(Kh + (size_t)((kb_) + ch * 8 + lrow8) * H_ + swl,                \
              &Ks[buf][ch * 512]);                                             \
      gload16(Vh + (size_t)(ch * 8 + lrow8) * S_ + (kb_) + swl,                \
              &Vs[buf][ch * 512]);                                             \
    }                                                                          \
  } while (0)

  // Q fragments (B-operand for swapped QK^T: n=lan=q, k=grp*8+j (+32*kf))
  bf16x8 qa[2][2];
#pragma unroll
  for (int qt = 0; qt < 2; ++qt)
#pragma unroll
    for (int kf = 0; kf < 2; ++kf)
      qa[qt][kf] = *(const bf16x8*)(Qh + (size_t)(qw + qt * 16 + lan) * H_ + grp * 8 + kf * 32);

  f32x4 o[2][4];
  float psum[2] = {0.0f, 0.0f};
#pragma unroll
  for (int qt = 0; qt < 2; ++qt)
#pragma unroll
    for (int hf = 0; hf < 4; ++hf) o[qt][hf] = zero4();

  bf16* Pw = &Ps[w][0];

  STAGE(0, t0 * 64);
  for (int tt = t0; tt < t1; ++tt) {
    const int kb = tt * 64;
    const int cur = (tt - t0) & 1;
    if (tt + 1 < t1) {
      STAGE(cur ^ 1, kb + 64);
      asm volatile("s_waitcnt vmcnt(4)" ::: "memory");
    } else {
      asm volatile("s_waitcnt vmcnt(0)" ::: "memory");
    }
    __builtin_amdgcn_s_barrier();

    if (kb <= qw + 31) {
      const bf16* Kc = &Ks[cur][0];
      const bf16* Vc = &Vs[cur][0];

      // --- swapped QK^T: s2[k2][qt], col=lan=q, row=grp*4+r=k ---
      f32x4 s2[4][2];
#pragma unroll
      for (int k2 = 0; k2 < 4; ++k2)
#pragma unroll
        for (int qt = 0; qt < 2; ++qt) s2[k2][qt] = zero4();
      __builtin_amdgcn_s_setprio(1);
#pragma unroll
      for (int kf = 0; kf < 2; ++kf) {
        bf16x8 kfr[4];
#pragma unroll
        for (int k2 = 0; k2 < 4; ++k2)
          kfr[k2] = *(const bf16x8*)(Kc + (k2 * 16 + lan) * 64 + (((grp + kf * 4) ^ l7) << 3));
#pragma unroll
        for (int k2 = 0; k2 < 4; ++k2)
#pragma unroll
          for (int qt = 0; qt < 2; ++qt)
            s2[k2][qt] = mfma16(kfr[k2], qa[qt][kf], s2[k2][qt]);
      }
      __builtin_amdgcn_s_setprio(0);

      // --- p = exp2(s) (Q pre-scaled), diag-mask, psum, pack -> b64 write ---
      const bool maskt = (kb + 63 > qw);
#pragma unroll
      for (int qt = 0; qt < 2; ++qt) {
        const int q_g = qw + qt * 16 + lan;
#pragma unroll
        for (int k2 = 0; k2 < 4; ++k2) {
          f32x4 p;
#pragma unroll
          for (int r = 0; r < 4; ++r) p[r] = exp2f(s2[k2][qt][r]);
          if (maskt) {
            const int kg0 = kb + k2 * 16 + grp * 4;
#pragma unroll
            for (int r = 0; r < 4; ++r)
              if (kg0 + r > q_g) p[r] = 0.0f;
          }
          psum[qt] += (p[0] + p[1]) + (p[2] + p[3]);
          unsigned plo, phi;
          asm("v_cvt_pk_bf16_f32 %0, %1, %2" : "=v"(plo) : "v"(p[0]), "v"(p[1]));
          asm("v_cvt_pk_bf16_f32 %0, %1, %2" : "=v"(phi) : "v"(p[2]), "v"(p[3]));
          uint2 u; u.x = plo; u.y = phi;
          *(uint2*)(Pw + (qt * 16 + lan) * 72 + k2 * 16 + grp * 4) = u;
        }
      }

      // --- PV ---
      __builtin_amdgcn_s_setprio(1);
#pragma unroll
      for (int ks = 0; ks < 2; ++ks) {
        bf16x8 pa[2], vb[4];
#pragma unroll
        for (int qt = 0; qt < 2; ++qt)
          pa[qt] = *(const bf16x8*)(Pw + (qt * 16 + lan) * 72 + grp * 8 + ks * 32);
#pragma unroll
        for (int hf = 0; hf < 4; ++hf)
          vb[hf] = *(const bf16x8*)(Vc + (hf * 16 + lan) * 64 + (((grp + ks * 4) ^ l7) << 3));
#pragma unroll
        for (int qt = 0; qt < 2; ++qt)
#pragma unroll
          for (int hf = 0; hf < 4; ++hf)
            o[qt][hf] = mfma16(pa[qt], vb[hf], o[qt][hf]);
      }
      __builtin_amdgcn_s_setprio(0);
    }
    __builtin_amdgcn_s_barrier();
  }
#undef STAGE

  // psum: reduce over grp (lanes sharing lan); q = qt*16+lan
#pragma unroll
  for (int qt = 0; qt < 2; ++qt) {
    psum[qt] += __shfl_xor(psum[qt], 16);
    psum[qt] += __shfl_xor(psum[qt], 32);
  }

  if (qq == 2) {
    // final: o = (o_causal + SufV) / (psum + (2047-q))
    const size_t outbase = (size_t)(hd >> 4) * S_ * (N_ * H_) + (size_t)(hd & 15) * H_;
#pragma unroll
    for (int qt = 0; qt < 2; ++qt) {
#pragma unroll
      for (int r = 0; r < 4; ++r) {
        const int q_g = qw + qt * 16 + grp * 4 + r;
        const float ps = __shfl(psum[qt], grp * 4 + r);
        const float inv = 1.0f / (ps + (float)(2047 - q_g));
#pragma unroll
        for (int hf = 0; hf < 4; ++hf) {
          const int h = hf * 16 + lan;
          const float suf = (float)Sufh[(size_t)q_g * H_ + h];
          Wtd[outbase + (size_t)q_g * (N_ * H_) + h] = (bf16)((o[qt][hf][r] + suf) * inv);
        }
      }
    }
  } else {
    // partial: raw fp32 o + row psums
    float* Po = (qq == 0) ? PoA : PoB;
    float* Pp = (qq == 0) ? PpA : PpB;
    const int pb = (hd * 8 + (x - 8)) * 128 + w * 32;
#pragma unroll
    for (int qt = 0; qt < 2; ++qt) {
#pragma unroll
      for (int r = 0; r < 4; ++r) {
        const int rl = qt * 16 + grp * 4 + r;
        const float ps = __shfl(psum[qt], grp * 4 + r);
        if (lan == 0) Pp[pb + rl] = ps;
#pragma unroll
        for (int hf = 0; hf < 4; ++hf)
          Po[(size_t)(pb + rl) * 64 + hf * 16 + lan] = o[qt][hf][r];
      }
    }
  }
}

// ---------------------------------------------------------------------------
// Combine: for x in 8..15, Wtd = (PoA + PoB + Suf) / (PpA + PpB + 2047-q).
// ---------------------------------------------------------------------------
__global__ __launch_bounds__(256) void combine_kernel(
    const float* __restrict__ PoA, const float* __restrict__ PoB,
    const float* __restrict__ PpA, const float* __restrict__ PpB,
    const bf16* __restrict__ Suf, bf16* __restrict__ Wtd) {
  const int hd = blockIdx.x >> 3, xi = blockIdx.x & 7;
  const int x = xi + 8;
  const int pb = (hd * 8 + xi) * 128;
  const size_t outbase = (size_t)(hd >> 4) * S_ * (N_ * H_) + (size_t)(hd & 15) * H_;
#pragma unroll
  for (int it = 0; it < 8; ++it) {
    const int e = it * 256 + threadIdx.x;  // 0..2047 float4 units
    const int rl = e >> 4, h4 = (e & 15) * 4;
    const int q_g = x * 128 + rl;
    const float Z = PpA[pb + rl] + PpB[pb + rl] + (float)(2047 - q_g);
    const float inv = 1.0f / Z;
    const float4 a = *(const float4*)(PoA + (size_t)(pb + rl) * 64 + h4);
    const float4 b = *(const float4*)(PoB + (size_t)(pb + rl) * 64 + h4);
    const bf16x4 s4 = *(const bf16x4*)(Suf + ((size_t)hd * S_ + q_g) * 64 + h4);
    bf16x4 ov;
    ov[0] = (bf16)((a.x + b.x + (float)s4[0]) * inv);
    ov[1] = (bf16)((a.y + b.y + (float)s4[1]) * inv);
    ov[2] = (bf16)((a.z + b.z + (float)s4[2]) * inv);
    ov[3] = (bf16)((a.w + b.w + (float)s4[3]) * inv);
    *(bf16x4*)(Wtd + outbase + (size_t)q_g * (N_ * H_) + h4) = ov;
  }
}

// ---------------------------------------------------------------------------
extern "C" void kernel_launch(void* const* d_in, const int* in_sizes, int n_in,
                              void* d_out, int out_size, void* d_ws, size_t ws_size,
                              hipStream_t stream) {
  const float* residual = (const float*)d_in[0];
  const float* Wk = (const float*)d_in[1];
  const float* Wq = (const float*)d_in[2];
  const float* Wv = (const float*)d_in[3];
  const float* Wo = (const float*)d_in[4];
  const float* Bk = (const float*)d_in[5];
  const float* Bq = (const float*)d_in[6];
  const float* Bv = (const float*)d_in[7];
  const float* Bo = (const float*)d_in[8];
  float* outp = (float*)d_out;

  // ws layout (peak 48MB — proven safe; do NOT exceed):
  //   [ 0.. 8) Abf (prep out, gemm_proj A)       -> Wtd (attn/combine out)
  //   [ 8..10) Wot (live to end)
  //   [10..16) Wkt (gemm_proj B, [3072][1024])   -> PpA, PpB, tot
  //   [16..24) Kp   [24..32) Qp
  //   [32..40) Vp (proj V) -> in-place Suf (bf16) via sufv_scan
  //   [40..48) Vtp
  // d_out (16MB fp32): PoA [0..8MB) + PoB [8..16MB) until gemm_out overwrites.
  char* ws = (char*)d_ws;
  const size_t MB = 1024 * 1024;
  bf16* Abf = (bf16*)(ws + 0 * MB);
  bf16* Wot = (bf16*)(ws + 8 * MB);
  bf16* Wkt = (bf16*)(ws + 10 * MB);
  bf16* Kp  = (bf16*)(ws + 16 * MB);
  bf16* Qp  = (bf16*)(ws + 24 * MB);
  bf16* Vp  = (bf16*)(ws + 32 * MB);
  bf16* Vtp = (bf16*)(ws + 40 * MB);
  bf16* Wtd = Abf;                                   // dead after gemm_proj
  float* PpA = (float*)(ws + 10 * MB);               // [32][8][128] (128KB)
  float* PpB = (float*)(ws + 10 * MB + 128 * 1024);  // (128KB)
  float* tot = (float*)(ws + 10 * MB + 256 * 1024);  // [32][64][64] (512KB)
  bf16* Suf = Vp;                                    // in-place over Vp
  float* PoA = (float*)d_out;                        // [32][8][128][64] (8MB)
  float* PoB = (float*)d_out + 2 * 1024 * 1024;      // (8MB)
  (void)in_sizes; (void)n_in; (void)out_size; (void)ws_size;

  // prep: cvt + QKV weight transpose + Wo transpose (merged)
  prep_kernel<<<3072, 256, 0, stream>>>(residual, Abf, Wk, Wq, Wv, Wkt, Wo, Wot);

  // QKV projections — 256² tiles, grid 192 (R12-measured best), Q pre-scaled
  gemm_proj_kernel<<<192, 512, 0, stream>>>(Abf, Wkt, Bk, Bq, Bv, Kp);

  // V-work: sufv column totals + V transpose (merged; both read Vp)
  vwork_kernel<<<3072, 256, 0, stream>>>(Vp, tot, Vtp);

  // in-place: Vp becomes Suf (bf16)
  sufv_scan_kernel<<<dim3(32, 64), 64, 0, stream>>>(Vp, tot);

  // attention: split-k, balanced (34 tiles per CU triple)
  attn_kernel<<<768, 256, 0, stream>>>(Qp, Kp, Vtp, Suf, Wtd, PoA, PoB, PpA, PpB);

  // combine halves for x >= 8
  combine_kernel<<<256, 256, 0, stream>>>(PoA, PoB, PpA, PpB, Suf, Wtd);

  // output projection v2 — 128x64 tiles, grid 512 (2 blocks/CU)
  gemm_out_kernel<<<512, 256, 0, stream>>>(Wtd, Wot, Bo, outp);
}

// Round 16
// 136.145 us; speedup vs baseline: 1.1100x; 1.0497x over previous
//
#include <hip/hip_runtime.h>
#include <hip/hip_bf16.h>
#include <cmath>

typedef __bf16 bf16;
typedef __attribute__((ext_vector_type(4))) __bf16 bf16x4;
typedef __attribute__((ext_vector_type(8))) __bf16 bf16x8;
typedef __attribute__((ext_vector_type(4))) float f32x4;

#define B_ 2
#define S_ 2048
#define D_ 1024
#define N_ 16
#define H_ 64
// 0.125 * log2(e): folded into Q at projection so QK^T emits exp2-domain scores
#define QSCALE 0.18033688011112042f

__device__ __forceinline__ void gload16(const bf16* g, bf16* l) {
  __builtin_amdgcn_global_load_lds(
      (const __attribute__((address_space(1))) void*)(g),
      (__attribute__((address_space(3))) void*)(l), 16, 0, 0);
}

__device__ __forceinline__ f32x4 mfma16(bf16x8 a, bf16x8 b, f32x4 c) {
  return __builtin_amdgcn_mfma_f32_16x16x32_bf16(a, b, c, 0, 0, 0);
}

__device__ __forceinline__ f32x4 zero4() {
  f32x4 v = {0.0f, 0.0f, 0.0f, 0.0f};
  return v;
}

// ---------------------------------------------------------------------------
// Prep (merged, 3072 blocks x 256):
//   bi <  2048: residual fp32 -> bf16 (8 elems/thread)
//   2048..2815: QKV weight transpose, head z: [1024][64] fp32 -> [64][1024] bf16
//   2816..3071: Wo transpose: [1024][1024] fp32 -> bf16 transposed
// ---------------------------------------------------------------------------
__global__ __launch_bounds__(256) void prep_kernel(
    const float* __restrict__ residual, bf16* __restrict__ Abf,
    const float* __restrict__ Wk, const float* __restrict__ Wq,
    const float* __restrict__ Wv, bf16* __restrict__ Wkt,
    const float* __restrict__ Wo, bf16* __restrict__ Wot) {
  __shared__ bf16 t[64][72];
  const int bi = blockIdx.x;
  if (bi < 2048) {
    const int id = bi * 256 + threadIdx.x;
    const float4* p = (const float4*)(residual + (size_t)id * 8);
    float4 v0 = p[0], v1 = p[1];
    bf16x8 o;
    o[0] = (bf16)v0.x; o[1] = (bf16)v0.y; o[2] = (bf16)v0.z; o[3] = (bf16)v0.w;
    o[4] = (bf16)v1.x; o[5] = (bf16)v1.y; o[6] = (bf16)v1.z; o[7] = (bf16)v1.w;
    *(bf16x8*)(Abf + (size_t)id * 8) = o;
    return;
  }
  const float* ing; bf16* outg; int C, r0, c0;
  if (bi < 2816) {
    const int idx = bi - 2048, z = idx >> 4, xr = idx & 15;
    const float* W = (z < 16) ? Wk : (z < 32) ? Wq : Wv;
    ing = W + (size_t)(z & 15) * (1024 * 64);
    outg = Wkt + (size_t)z * (64 * 1024);
    C = 64; r0 = xr * 64; c0 = 0;
  } else {
    const int idx = bi - 2816, xr = idx & 15, yc = idx >> 4;
    ing = Wo; outg = Wot; C = 1024; r0 = xr * 64; c0 = yc * 64;
  }
  const int t8 = threadIdx.x & 7, trow = threadIdx.x >> 3;
#pragma unroll
  for (int p = 0; p < 2; ++p) {
    int r = trow + p * 32;
    const float4* src = (const float4*)(ing + (size_t)(r0 + r) * C + c0 + t8 * 8);
    float4 v0 = src[0], v1 = src[1];
    bf16x8 o;
    o[0] = (bf16)v0.x; o[1] = (bf16)v0.y; o[2] = (bf16)v0.z; o[3] = (bf16)v0.w;
    o[4] = (bf16)v1.x; o[5] = (bf16)v1.y; o[6] = (bf16)v1.z; o[7] = (bf16)v1.w;
    *(bf16x8*)(&t[r][t8 * 8]) = o;
  }
  __syncthreads();
#pragma unroll
  for (int p = 0; p < 2; ++p) {
    int c = trow + p * 32;
    bf16x8 v;
#pragma unroll
    for (int j = 0; j < 8; ++j) v[j] = t[t8 * 8 + j][c];
    *(bf16x8*)(outg + (size_t)(c0 + c) * 1024 + r0 + t8 * 8) = v;
  }
}

// ---------------------------------------------------------------------------
// V-work (merged, 3072 blocks x 256):
//   bi < 2048: sufv_tot — per-(hd, 32-row seg) column totals of Vp,
//              written TRANSPOSED: tot[hd][h][seg] (contiguous segs for scan)
//   else     : bf16 transpose Vp [S][H] -> Vtp [H][S] per head
// ---------------------------------------------------------------------------
__global__ __launch_bounds__(256) void vwork_kernel(
    const bf16* __restrict__ Vp, float* __restrict__ tot,
    bf16* __restrict__ Vtp) {
  __shared__ bf16 t[64][72];
  __shared__ float red[4][64];
  const int bi = blockIdx.x;
  if (bi < 2048) {
    const int hd = bi >> 6, seg = bi & 63;
    const int h = threadIdx.x & 63, sub = threadIdx.x >> 6;
    const bf16* Vh = Vp + (size_t)hd * S_ * H_;
    float a = 0.0f;
    const int k0 = seg * 32 + sub * 8;
#pragma unroll
    for (int k = 0; k < 8; ++k) a += (float)Vh[(size_t)(k0 + k) * H_ + h];
    red[sub][h] = a;
    __syncthreads();
    if (sub == 0)
      tot[(hd * 64 + h) * 64 + seg] = red[0][h] + red[1][h] + red[2][h] + red[3][h];
    return;
  }
  const int idx = bi - 2048, z = idx >> 5, xr = idx & 31;
  const bf16* ing = Vp + (size_t)z * (S_ * H_);
  bf16* outg = Vtp + (size_t)z * (S_ * H_);
  const int r0 = xr * 64;
  const int t8 = threadIdx.x & 7, trow = threadIdx.x >> 3;
#pragma unroll
  for (int p = 0; p < 2; ++p) {
    int r = trow + p * 32;
    bf16x8 v = *(const bf16x8*)(ing + (size_t)(r0 + r) * 64 + t8 * 8);
    *(bf16x8*)(&t[r][t8 * 8]) = v;
  }
  __syncthreads();
#pragma unroll
  for (int p = 0; p < 2; ++p) {
    int c = trow + p * 32;
    bf16x8 v;
#pragma unroll
    for (int j = 0; j < 8; ++j) v[j] = t[t8 * 8 + j][c];
    *(bf16x8*)(outg + (size_t)c * 2048 + r0 + t8 * 8) = v;
  }
}

// ---------------------------------------------------------------------------
// Suffix-V scan: Suf[hd][q][h] = sum_{k>q} V[hd][k][h], bf16 IN-PLACE over Vp.
// Prefix over higher segments now reads CONTIGUOUS tot[hd][h][0..63] via 16
// independent float4 loads (was 63 serially-dependent 4KB-strided loads).
// Same ascending add order -> bit-identical numerics.
// ---------------------------------------------------------------------------
__global__ __launch_bounds__(64) void sufv_scan_kernel(
    bf16* __restrict__ VS, const float* __restrict__ tot) {
  const int hd = blockIdx.x, seg = blockIdx.y, h = threadIdx.x;
  bf16* Vh = VS + (size_t)hd * S_ * H_;  // in: V, out: Suf (in-place)
  const float* th = tot + ((size_t)hd * 64 + h) * 64;
  float tv[64];
#pragma unroll
  for (int j4 = 0; j4 < 16; ++j4) {
    const float4 v4 = *(const float4*)(th + j4 * 4);
    tv[j4 * 4 + 0] = v4.x; tv[j4 * 4 + 1] = v4.y;
    tv[j4 * 4 + 2] = v4.z; tv[j4 * 4 + 3] = v4.w;
  }
  float a = 0.0f;
#pragma unroll
  for (int j = 0; j < 64; ++j)
    if (j > seg) a += tv[j];
  for (int k = seg * 32 + 31; k >= seg * 32; --k) {
    const float v = (float)Vh[(size_t)k * H_ + h];  // read BEFORE overwrite
    Vh[(size_t)k * H_ + h] = (bf16)a;
    a += v;
  }
}

// ---------------------------------------------------------------------------
// QKV projection GEMM v2 (R11/R12-measured best: 256x256 tile, grid 192,
// 4-phase counted-vmcnt, XCD-remapped) + QSCALE on queries (for exp2 attn).
// ---------------------------------------------------------------------------
__global__ __launch_bounds__(512) void gemm_proj_kernel(
    const bf16* __restrict__ A, const bf16* __restrict__ Bt,
    const float* __restrict__ bk, const float* __restrict__ bq,
    const float* __restrict__ bv, bf16* __restrict__ proj_base) {
  __shared__ bf16 As[2][2][256 * 32];
  __shared__ bf16 Bs[2][2][256 * 32];
  const int tid = threadIdx.x;
  const int w = tid >> 6, l = tid & 63, lan = l & 15, grp = l >> 4;
  const int wm128 = (w >> 2) * 128, wn64 = (w & 3) * 64;
  const int bid = blockIdx.x;
  const int bid2 = (bid & 7) * 24 + (bid >> 3);  // XCD-contiguous remap
  const int m0 = (bid2 / 12) * 256, n0 = (bid2 % 12) * 256;
  const int zc = n0 >> 10;  // block-uniform (1024 % 256 == 0)
  const float* bias = (zc == 0) ? bk : (zc == 1 ? bq : bv);
  const float osc = (zc == 1) ? QSCALE : 1.0f;
  bf16* Out = proj_base + (size_t)zc * ((size_t)B_ * N_ * S_ * H_);
  const int posx = (grp ^ ((lan >> 1) & 3)) << 3;  // swizzled read chunk

#define STG(LDS_, GP_, rb_, buf_, kh_, kb_)                                    \
  do {                                                                         \
    _Pragma("unroll") for (int jj = 0; jj < 2; ++jj) {                         \
      const int ci = jj * 512 + tid;                                           \
      const int rw = ci >> 2, cp = ci & 3;                                     \
      const int gg = cp ^ ((rw >> 1) & 3);                                     \
      gload16(GP_ + (size_t)((rb_) + rw) * 1024 + (kb_) + (kh_) * 32 + gg * 8, \
              &LDS_[buf_][kh_][(jj * 512 + w * 64) * 8]);                      \
    }                                                                          \
  } while (0)

  f32x4 acc[8][4];
#pragma unroll
  for (int i = 0; i < 8; ++i)
#pragma unroll
    for (int jv = 0; jv < 4; ++jv) acc[i][jv] = zero4();

  bf16x8 b[4];

#define DO_PHASE(buf_, mq_, kk_, READB_)                                       \
  do {                                                                         \
    if (READB_) {                                                              \
      _Pragma("unroll") for (int nf = 0; nf < 4; ++nf)                         \
        b[nf] = *(const bf16x8*)(&Bs[buf_][kk_][(wn64 + nf * 16 + lan) * 32 + posx]); \
    }                                                                          \
    bf16x8 a[4];                                                               \
    _Pragma("unroll") for (int mf = 0; mf < 4; ++mf)                           \
      a[mf] = *(const bf16x8*)(&As[buf_][kk_][(wm128 + (mq_) * 64 + mf * 16 + lan) * 32 + posx]); \
    __builtin_amdgcn_s_setprio(1);                                             \
    _Pragma("unroll") for (int mf = 0; mf < 4; ++mf)                           \
      _Pragma("unroll") for (int nf = 0; nf < 4; ++nf)                         \
        acc[(mq_) * 4 + mf][nf] = mfma16(a[mf], b[nf], acc[(mq_) * 4 + mf][nf]); \
    __builtin_amdgcn_s_setprio(0);                                             \
  } while (0)

  // prologue: all 4 slots of K-step 0 into buf 0
  STG(As, A, m0, 0, 0, 0);
  STG(Bs, Bt, n0, 0, 0, 0);
  STG(As, A, m0, 0, 1, 0);
  STG(Bs, Bt, n0, 0, 1, 0);

  for (int t = 0; t < 15; ++t) {
    const int buf = t & 1;
    const int nkb = (t + 1) * 64;
    STG(As, A, m0, buf ^ 1, 0, nkb);
    asm volatile("s_waitcnt vmcnt(6)" ::: "memory");
    __builtin_amdgcn_s_barrier();
    asm volatile("" ::: "memory");
    DO_PHASE(buf, 0, 0, true);
    STG(Bs, Bt, n0, buf ^ 1, 0, nkb);
    asm volatile("" ::: "memory");
    __builtin_amdgcn_s_barrier();
    asm volatile("" ::: "memory");
    DO_PHASE(buf, 1, 0, false);
    STG(As, A, m0, buf ^ 1, 1, nkb);
    asm volatile("s_waitcnt vmcnt(6)" ::: "memory");
    __builtin_amdgcn_s_barrier();
    asm volatile("" ::: "memory");
    DO_PHASE(buf, 0, 1, true);
    STG(Bs, Bt, n0, buf ^ 1, 1, nkb);
    asm volatile("" ::: "memory");
    __builtin_amdgcn_s_barrier();
    asm volatile("" ::: "memory");
    DO_PHASE(buf, 1, 1, false);
  }
  {
    asm volatile("s_waitcnt vmcnt(4)" ::: "memory");
    __builtin_amdgcn_s_barrier();
    asm volatile("" ::: "memory");
    DO_PHASE(1, 0, 0, true);
    DO_PHASE(1, 1, 0, false);
    asm volatile("s_waitcnt vmcnt(0)" ::: "memory");
    __builtin_amdgcn_s_barrier();
    asm volatile("" ::: "memory");
    DO_PHASE(1, 0, 1, true);
    DO_PHASE(1, 1, 1, false);
  }
#undef STG
#undef DO_PHASE

  // epilogue: scatter to [z][b][n][s][h] + bias (+QSCALE for queries)
#pragma unroll
  for (int nf = 0; nf < 4; ++nf) {
    const int c10 = (n0 + wn64 + nf * 16 + lan) & 1023;
    const float bs = bias[c10];
    const int n = c10 >> 6, h = c10 & 63;
#pragma unroll
    for (int am = 0; am < 8; ++am) {
#pragma unroll
      for (int r = 0; r < 4; ++r) {
        const int m = m0 + wm128 + am * 16 + grp * 4 + r;
        const int bb = m >> 11, s = m & 2047;
        Out[((size_t)((bb * N_ + n) * S_ + s)) * H_ + h] = (bf16)((acc[am][nf][r] + bs) * osc);
      }
    }
  }
}

// ---------------------------------------------------------------------------
// Output projection GEMM v2: 128x64 tiles, grid 512 = 2 blocks/CU.
// ---------------------------------------------------------------------------
__global__ __launch_bounds__(256) void gemm_out_kernel(
    const bf16* __restrict__ A, const bf16* __restrict__ Bt,
    const float* __restrict__ bias, float* __restrict__ Out) {
  __shared__ bf16 As[128 * 64];
  __shared__ bf16 Bs[64 * 64];
  const int tid = threadIdx.x;
  const int w = tid >> 6, l = tid & 63, lan = l & 15, grp = l >> 4;
  const int mb = (w >> 1) * 64, nb = (w & 1) * 32;
  const int bid = blockIdx.x;
  const int bid2 = (bid & 7) * 64 + (bid >> 3);  // XCD-contiguous remap
  const int m0 = (bid2 >> 4) * 128, n0 = (bid2 & 15) * 64;
  const int lrow8 = l >> 3;
  const int swl = ((l & 7) ^ lrow8) * 8;
  const int l7 = lan & 7;

  f32x4 acc[4][2];
#pragma unroll
  for (int i = 0; i < 4; ++i)
#pragma unroll
    for (int j = 0; j < 2; ++j) acc[i][j] = zero4();

  for (int kb = 0; kb < 1024; kb += 64) {
    __syncthreads();
#pragma unroll
    for (int i = 0; i < 4; ++i) {
      int ch = w * 4 + i;
      gload16(A + (size_t)(m0 + ch * 8 + lrow8) * 1024 + kb + swl, As + ch * 512);
    }
#pragma unroll
    for (int i = 0; i < 2; ++i) {
      int ch = w * 2 + i;
      gload16(Bt + (size_t)(n0 + ch * 8 + lrow8) * 1024 + kb + swl, Bs + ch * 512);
    }
    __syncthreads();
#pragma unroll
    for (int kk = 0; kk < 2; ++kk) {
      bf16x8 a[4], b[2];
#pragma unroll
      for (int mf = 0; mf < 4; ++mf)
        a[mf] = *(const bf16x8*)(As + (mb + mf * 16 + lan) * 64 + (((grp + kk * 4) ^ l7) << 3));
#pragma unroll
      for (int nf = 0; nf < 2; ++nf)
        b[nf] = *(const bf16x8*)(Bs + (nb + nf * 16 + lan) * 64 + (((grp + kk * 4) ^ l7) << 3));
#pragma unroll
      for (int mf = 0; mf < 4; ++mf)
#pragma unroll
        for (int nf = 0; nf < 2; ++nf)
          acc[mf][nf] = mfma16(a[mf], b[nf], acc[mf][nf]);
    }
  }
#pragma unroll
  for (int nf = 0; nf < 2; ++nf) {
    int c = n0 + nb + nf * 16 + lan;
    float bs = bias[c];
#pragma unroll
    for (int mf = 0; mf < 4; ++mf) {
#pragma unroll
      for (int r = 0; r < 4; ++r) {
        int m = m0 + mb + mf * 16 + grp * 4 + r;
        Out[(size_t)m * 1024 + c] = acc[mf][nf][r] + bs;
      }
    }
  }
}

// ---------------------------------------------------------------------------
// Attention — R7 structure + exp2-domain Q (R13/R14/R15-measured ~50 µs).
//   quarter 0 (bi<256):  x=15-wv, k-tiles [0, x+1)     -> fp32 partial A
//   quarter 1 (bi<512):  x=15-wv, k-tiles [x+1, 2x+2)  -> fp32 partial B
//   quarter 2 (bi<768):  x=wv,    k-tiles [0, 2x+2)    -> final Wtd rows
// grid 768, block 256 (4 waves x 32 q-rows). Suf is bf16.
// ---------------------------------------------------------------------------
__global__ __launch_bounds__(256) void attn_kernel(
    const bf16* __restrict__ Qp, const bf16* __restrict__ Kp,
    const bf16* __restrict__ Vt, const bf16* __restrict__ Suf,
    bf16* __restrict__ Wtd, float* __restrict__ PoA, float* __restrict__ PoB,
    float* __restrict__ PpA, float* __restrict__ PpB) {
  __shared__ bf16 Ks[2][64 * 64];
  __shared__ bf16 Vs[2][64 * 64];
  __shared__ bf16 Ps[4][32 * 72];
  const int tid = threadIdx.x;
  const int w = tid >> 6, l = tid & 63, lan = l & 15, grp = l >> 4;
  const int bi = blockIdx.x;
  const int qq = bi >> 8;
  const int j = bi & 255;
  const int hd = j & 31, wv = j >> 5;
  int x, t0, t1;
  if (qq == 0)      { x = 15 - wv; t0 = 0;     t1 = x + 1; }
  else if (qq == 1) { x = 15 - wv; t0 = x + 1; t1 = 2 * x + 2; }
  else              { x = wv;      t0 = 0;     t1 = 2 * x + 2; }
  const int qw = x * 128 + w * 32;
  const bf16* Qh = Qp + (size_t)hd * S_ * H_;
  const bf16* Kh = Kp + (size_t)hd * S_ * H_;
  const bf16* Vh = Vt + (size_t)hd * H_ * S_;
  const bf16* Sufh = Suf + (size_t)hd * S_ * H_;
  const int lrow8 = l >> 3;
  const int swl = ((l & 7) ^ lrow8) * 8;
  const int l7 = lan & 7;

#define STAGE(buf, kb_)                                                        \
  do {                                                                         \
    _Pragma("unroll") for (int i2 = 0; i2 < 2; ++i2) {                         \
      int ch = w * 2 + i2;                                                     \
      gload16(Kh + (size_t)((kb_) + ch * 8 + lrow8) * H_ + swl,                \
              &Ks[buf][ch * 512]);                                             \
      gload16(Vh + (size_t)(ch * 8 + lrow8) * S_ + (kb_) + swl,                \
              &Vs[buf][ch * 512]);                                             \
    }                                                                          \
  } while (0)

  // Q fragments (B-operand for swapped QK^T: n=lan=q, k=grp*8+j (+32*kf))
  bf16x8 qa[2][2];
#pragma unroll
  for (int qt = 0; qt < 2; ++qt)
#pragma unroll
    for (int kf = 0; kf < 2; ++kf)
      qa[qt][kf] = *(const bf16x8*)(Qh + (size_t)(qw + qt * 16 + lan) * H_ + grp * 8 + kf * 32);

  f32x4 o[2][4];
  float psum[2] = {0.0f, 0.0f};
#pragma unroll
  for (int qt = 0; qt < 2; ++qt)
#pragma unroll
    for (int hf = 0; hf < 4; ++hf) o[qt][hf] = zero4();

  bf16* Pw = &Ps[w][0];

  STAGE(0, t0 * 64);
  for (int tt = t0; tt < t1; ++tt) {
    const int kb = tt * 64;
    const int cur = (tt - t0) & 1;
    if (tt + 1 < t1) {
      STAGE(cur ^ 1, kb + 64);
      asm volatile("s_waitcnt vmcnt(4)" ::: "memory");
    } else {
      asm volatile("s_waitcnt vmcnt(0)" ::: "memory");
    }
    __builtin_amdgcn_s_barrier();

    if (kb <= qw + 31) {
      const bf16* Kc = &Ks[cur][0];
      const bf16* Vc = &Vs[cur][0];

      // --- swapped QK^T: s2[k2][qt], col=lan=q, row=grp*4+r=k ---
      f32x4 s2[4][2];
#pragma unroll
      for (int k2 = 0; k2 < 4; ++k2)
#pragma unroll
        for (int qt = 0; qt < 2; ++qt) s2[k2][qt] = zero4();
      __builtin_amdgcn_s_setprio(1);
#pragma unroll
      for (int kf = 0; kf < 2; ++kf) {
        bf16x8 kfr[4];
#pragma unroll
        for (int k2 = 0; k2 < 4; ++k2)
          kfr[k2] = *(const bf16x8*)(Kc + (k2 * 16 + lan) * 64 + (((grp + kf * 4) ^ l7) << 3));
#pragma unroll
        for (int k2 = 0; k2 < 4; ++k2)
#pragma unroll
          for (int qt = 0; qt < 2; ++qt)
            s2[k2][qt] = mfma16(kfr[k2], qa[qt][kf], s2[k2][qt]);
      }
      __builtin_amdgcn_s_setprio(0);

      // --- p = exp2(s) (Q pre-scaled), diag-mask, psum, pack -> b64 write ---
      const bool maskt = (kb + 63 > qw);
#pragma unroll
      for (int qt = 0; qt < 2; ++qt) {
        const int q_g = qw + qt * 16 + lan;
#pragma unroll
        for (int k2 = 0; k2 < 4; ++k2) {
          f32x4 p;
#pragma unroll
          for (int r = 0; r < 4; ++r) p[r] = exp2f(s2[k2][qt][r]);
          if (maskt) {
            const int kg0 = kb + k2 * 16 + grp * 4;
#pragma unroll
            for (int r = 0; r < 4; ++r)
              if (kg0 + r > q_g) p[r] = 0.0f;
          }
          psum[qt] += (p[0] + p[1]) + (p[2] + p[3]);
          unsigned plo, phi;
          asm("v_cvt_pk_bf16_f32 %0, %1, %2" : "=v"(plo) : "v"(p[0]), "v"(p[1]));
          asm("v_cvt_pk_bf16_f32 %0, %1, %2" : "=v"(phi) : "v"(p[2]), "v"(p[3]));
          uint2 u; u.x = plo; u.y = phi;
          *(uint2*)(Pw + (qt * 16 + lan) * 72 + k2 * 16 + grp * 4) = u;
        }
      }

      // --- PV ---
      __builtin_amdgcn_s_setprio(1);
#pragma unroll
      for (int ks = 0; ks < 2; ++ks) {
        bf16x8 pa[2], vb[4];
#pragma unroll
        for (int qt = 0; qt < 2; ++qt)
          pa[qt] = *(const bf16x8*)(Pw + (qt * 16 + lan) * 72 + grp * 8 + ks * 32);
#pragma unroll
        for (int hf = 0; hf < 4; ++hf)
          vb[hf] = *(const bf16x8*)(Vc + (hf * 16 + lan) * 64 + (((grp + ks * 4) ^ l7) << 3));
#pragma unroll
        for (int qt = 0; qt < 2; ++qt)
#pragma unroll
          for (int hf = 0; hf < 4; ++hf)
            o[qt][hf] = mfma16(pa[qt], vb[hf], o[qt][hf]);
      }
      __builtin_amdgcn_s_setprio(0);
    }
    __builtin_amdgcn_s_barrier();
  }
#undef STAGE

  // psum: reduce over grp (lanes sharing lan); q = qt*16+lan
#pragma unroll
  for (int qt = 0; qt < 2; ++qt) {
    psum[qt] += __shfl_xor(psum[qt], 16);
    psum[qt] += __shfl_xor(psum[qt], 32);
  }

  if (qq == 2) {
    // final: o = (o_causal + SufV) / (psum + (2047-q))
    const size_t outbase = (size_t)(hd >> 4) * S_ * (N_ * H_) + (size_t)(hd & 15) * H_;
#pragma unroll
    for (int qt = 0; qt < 2; ++qt) {
#pragma unroll
      for (int r = 0; r < 4; ++r) {
        const int q_g = qw + qt * 16 + grp * 4 + r;
        const float ps = __shfl(psum[qt], grp * 4 + r);
        const float inv = 1.0f / (ps + (float)(2047 - q_g));
#pragma unroll
        for (int hf = 0; hf < 4; ++hf) {
          const int h = hf * 16 + lan;
          const float suf = (float)Sufh[(size_t)q_g * H_ + h];
          Wtd[outbase + (size_t)q_g * (N_ * H_) + h] = (bf16)((o[qt][hf][r] + suf) * inv);
        }
      }
    }
  } else {
    // partial: raw fp32 o + row psums
    float* Po = (qq == 0) ? PoA : PoB;
    float* Pp = (qq == 0) ? PpA : PpB;
    const int pb = (hd * 8 + (x - 8)) * 128 + w * 32;
#pragma unroll
    for (int qt = 0; qt < 2; ++qt) {
#pragma unroll
      for (int r = 0; r < 4; ++r) {
        const int rl = qt * 16 + grp * 4 + r;
        const float ps = __shfl(psum[qt], grp * 4 + r);
        if (lan == 0) Pp[pb + rl] = ps;
#pragma unroll
        for (int hf = 0; hf < 4; ++hf)
          Po[(size_t)(pb + rl) * 64 + hf * 16 + lan] = o[qt][hf][r];
      }
    }
  }
}

// ---------------------------------------------------------------------------
// Combine: for x in 8..15, Wtd = (PoA + PoB + Suf) / (PpA + PpB + 2047-q).
// ---------------------------------------------------------------------------
__global__ __launch_bounds__(256) void combine_kernel(
    const float* __restrict__ PoA, const float* __restrict__ PoB,
    const float* __restrict__ PpA, const float* __restrict__ PpB,
    const bf16* __restrict__ Suf, bf16* __restrict__ Wtd) {
  const int hd = blockIdx.x >> 3, xi = blockIdx.x & 7;
  const int x = xi + 8;
  const int pb = (hd * 8 + xi) * 128;
  const size_t outbase = (size_t)(hd >> 4) * S_ * (N_ * H_) + (size_t)(hd & 15) * H_;
#pragma unroll
  for (int it = 0; it < 8; ++it) {
    const int e = it * 256 + threadIdx.x;  // 0..2047 float4 units
    const int rl = e >> 4, h4 = (e & 15) * 4;
    const int q_g = x * 128 + rl;
    const float Z = PpA[pb + rl] + PpB[pb + rl] + (float)(2047 - q_g);
    const float inv = 1.0f / Z;
    const float4 a = *(const float4*)(PoA + (size_t)(pb + rl) * 64 + h4);
    const float4 b = *(const float4*)(PoB + (size_t)(pb + rl) * 64 + h4);
    const bf16x4 s4 = *(const bf16x4*)(Suf + ((size_t)hd * S_ + q_g) * 64 + h4);
    bf16x4 ov;
    ov[0] = (bf16)((a.x + b.x + (float)s4[0]) * inv);
    ov[1] = (bf16)((a.y + b.y + (float)s4[1]) * inv);
    ov[2] = (bf16)((a.z + b.z + (float)s4[2]) * inv);
    ov[3] = (bf16)((a.w + b.w + (float)s4[3]) * inv);
    *(bf16x4*)(Wtd + outbase + (size_t)q_g * (N_ * H_) + h4) = ov;
  }
}

// ---------------------------------------------------------------------------
extern "C" void kernel_launch(void* const* d_in, const int* in_sizes, int n_in,
                              void* d_out, int out_size, void* d_ws, size_t ws_size,
                              hipStream_t stream) {
  const float* residual = (const float*)d_in[0];
  const float* Wk = (const float*)d_in[1];
  const float* Wq = (const float*)d_in[2];
  const float* Wv = (const float*)d_in[3];
  const float* Wo = (const float*)d_in[4];
  const float* Bk = (const float*)d_in[5];
  const float* Bq = (const float*)d_in[6];
  const float* Bv = (const float*)d_in[7];
  const float* Bo = (const float*)d_in[8];
  float* outp = (float*)d_out;

  // ws layout (peak 48MB — proven safe; do NOT exceed):
  //   [ 0.. 8) Abf (prep out, gemm_proj A)       -> Wtd (attn/combine out)
  //   [ 8..10) Wot (live to end)
  //   [10..16) Wkt (gemm_proj B, [3072][1024])   -> PpA, PpB, tot
  //   [16..24) Kp   [24..32) Qp
  //   [32..40) Vp (proj V) -> in-place Suf (bf16) via sufv_scan
  //   [40..48) Vtp
  // d_out (16MB fp32): PoA [0..8MB) + PoB [8..16MB) until gemm_out overwrites.
  char* ws = (char*)d_ws;
  const size_t MB = 1024 * 1024;
  bf16* Abf = (bf16*)(ws + 0 * MB);
  bf16* Wot = (bf16*)(ws + 8 * MB);
  bf16* Wkt = (bf16*)(ws + 10 * MB);
  bf16* Kp  = (bf16*)(ws + 16 * MB);
  bf16* Qp  = (bf16*)(ws + 24 * MB);
  bf16* Vp  = (bf16*)(ws + 32 * MB);
  bf16* Vtp = (bf16*)(ws + 40 * MB);
  bf16* Wtd = Abf;                                   // dead after gemm_proj
  float* PpA = (float*)(ws + 10 * MB);               // [32][8][128] (128KB)
  float* PpB = (float*)(ws + 10 * MB + 128 * 1024);  // (128KB)
  float* tot = (float*)(ws + 10 * MB + 256 * 1024);  // [32][64(h)][64(seg)] (512KB)
  bf16* Suf = Vp;                                    // in-place over Vp
  float* PoA = (float*)d_out;                        // [32][8][128][64] (8MB)
  float* PoB = (float*)d_out + 2 * 1024 * 1024;      // (8MB)
  (void)in_sizes; (void)n_in; (void)out_size; (void)ws_size;

  // prep: cvt + QKV weight transpose + Wo transpose (merged)
  prep_kernel<<<3072, 256, 0, stream>>>(residual, Abf, Wk, Wq, Wv, Wkt, Wo, Wot);

  // QKV projections — 256² tiles, grid 192 (R12-measured best), Q pre-scaled
  gemm_proj_kernel<<<192, 512, 0, stream>>>(Abf, Wkt, Bk, Bq, Bv, Kp);

  // V-work: sufv column totals (transposed tot) + V transpose (merged)
  vwork_kernel<<<3072, 256, 0, stream>>>(Vp, tot, Vtp);

  // in-place: Vp becomes Suf (bf16); prefix now 16 independent float4 loads
  sufv_scan_kernel<<<dim3(32, 64), 64, 0, stream>>>(Vp, tot);

  // attention: split-k, balanced (34 tiles per CU triple)
  attn_kernel<<<768, 256, 0, stream>>>(Qp, Kp, Vtp, Suf, Wtd, PoA, PoB, PpA, PpB);

  // combine halves for x >= 8
  combine_kernel<<<256, 256, 0, stream>>>(PoA, PoB, PpA, PpB, Suf, Wtd);

  // output projection v2 — 128x64 tiles, grid 512 (2 blocks/CU)
  gemm_out_kernel<<<512, 256, 0, stream>>>(Wtd, Wot, Bo, outp);
}